// Round 1
// baseline (1754.474 us; speedup 1.0000x reference)
//
#include <hip/hip_runtime.h>
#include <hip/hip_bf16.h>

#define NTOK 4096   // B*N
#define NN   512
#define DD   256

// ---------------------------------------------------------------------------
// K0: detect whether relations_mask is 1-byte bool or 4-byte int.
// If int32 (values 0/1), every byte at offset i%4!=0 is zero.
// If bool bytes (~90% ones), many of those bytes are nonzero.
__global__ void detect_mask_kernel(const unsigned char* __restrict__ m, int* __restrict__ flag) {
    __shared__ int f;
    if (threadIdx.x == 0) f = 0;
    __syncthreads();
    int any = 0;
    for (int i = threadIdx.x; i < 4096; i += 256) {
        if ((i & 3) != 0 && m[i] != 0) any = 1;
    }
    if (any) atomicOr(&f, 1);
    __syncthreads();
    if (threadIdx.x == 0) *flag = f;   // 1 => byte mask, 0 => int32 mask
}

// ---------------------------------------------------------------------------
// K1: x[row,d] = relu(sum_e embed[tok[row]][e] * W_in[e][d] + b_in[d])
// 8 rows per block, 256 threads (one output column each).
__global__ __launch_bounds__(256) void embed_proj_kernel(
    const int* __restrict__ tok, const float* __restrict__ embed,
    const float* __restrict__ W_in, const float* __restrict__ b_in,
    float* __restrict__ x)
{
    __shared__ float emb[8][304];
    __shared__ int tloc[8];
    const int t = threadIdx.x;
    const int r0 = blockIdx.x * 8;
    if (t < 8) tloc[t] = tok[r0 + t];
    __syncthreads();
    for (int i = t; i < 8 * 300; i += 256) {
        int r = i / 300, e = i - r * 300;
        emb[r][e] = embed[(size_t)tloc[r] * 300 + e];
    }
    __syncthreads();
    float acc[8] = {0.f,0.f,0.f,0.f,0.f,0.f,0.f,0.f};
    const int d = t;
    for (int e = 0; e < 300; ++e) {
        float w = W_in[e * 256 + d];
#pragma unroll
        for (int r = 0; r < 8; ++r) acc[r] += emb[r][e] * w;
    }
    const float bb = b_in[d];
#pragma unroll
    for (int r = 0; r < 8; ++r) {
        float o = acc[r] + bb;
        o = o > 0.f ? o : 0.f;
        x[(size_t)(r0 + r) * 256 + d] = o;
    }
}

// ---------------------------------------------------------------------------
// K2: generic fp32 GEMM  C[M,Nc] = act(A[M,K] @ W + bias)
// W is split across up to 3 matrices of ncPerW columns each (for fused QKV).
// Tile: BM=128 x BN=64, BK=16, 256 threads, 8x4 microtile.
__global__ __launch_bounds__(256) void gemm_kernel(
    const float* __restrict__ A,
    const float* __restrict__ W0, const float* __restrict__ W1p, const float* __restrict__ W2p,
    int ncPerW,
    const float* __restrict__ bias,
    float* __restrict__ C, int M, int K, int Nc, int relu)
{
    const int t = threadIdx.x;
    const int bn = blockIdx.x, bm = blockIdx.y;
    const int r0 = bm * 128, c0 = bn * 64;

    const float* W = W0;
    int cW = c0;
    if (c0 >= 2 * ncPerW)      { W = W2p; cW = c0 - 2 * ncPerW; }
    else if (c0 >= ncPerW)     { W = W1p; cW = c0 - ncPerW; }

    __shared__ float As[16][132];
    __shared__ float Ws[16][68];

    const int tx = t & 15, ty = t >> 4;
    float acc[8][4];
#pragma unroll
    for (int i = 0; i < 8; ++i)
#pragma unroll
        for (int j = 0; j < 4; ++j) acc[i][j] = 0.f;

    for (int k0 = 0; k0 < K; k0 += 16) {
        // stage A tile 128x16 (transposed into LDS)
#pragma unroll
        for (int ii = 0; ii < 2; ++ii) {
            int f4 = t * 2 + ii;            // 0..511
            int row = f4 >> 2;
            int kk4 = (f4 & 3) * 4;
            const float4 av = *(const float4*)(A + (size_t)(r0 + row) * K + k0 + kk4);
            As[kk4 + 0][row] = av.x;
            As[kk4 + 1][row] = av.y;
            As[kk4 + 2][row] = av.z;
            As[kk4 + 3][row] = av.w;
        }
        // stage W tile 16x64
        {
            int kk = t >> 4, c4 = (t & 15) * 4;
            const float4 wv = *(const float4*)(W + (size_t)(k0 + kk) * ncPerW + cW + c4);
            *(float4*)&Ws[kk][c4] = wv;
        }
        __syncthreads();
#pragma unroll
        for (int kk = 0; kk < 16; ++kk) {
            float4 wv = *(const float4*)&Ws[kk][tx * 4];
            float4 a0 = *(const float4*)&As[kk][ty * 8];
            float4 a1 = *(const float4*)&As[kk][ty * 8 + 4];
            float ar[8] = {a0.x, a0.y, a0.z, a0.w, a1.x, a1.y, a1.z, a1.w};
            float wr[4] = {wv.x, wv.y, wv.z, wv.w};
#pragma unroll
            for (int i = 0; i < 8; ++i)
#pragma unroll
                for (int j = 0; j < 4; ++j) acc[i][j] += ar[i] * wr[j];
        }
        __syncthreads();
    }
    float4 bv = make_float4(0.f, 0.f, 0.f, 0.f);
    if (bias) bv = *(const float4*)(bias + c0 + tx * 4);
#pragma unroll
    for (int i = 0; i < 8; ++i) {
        int row = r0 + ty * 8 + i;
        float4 o;
        o.x = acc[i][0] + bv.x;
        o.y = acc[i][1] + bv.y;
        o.z = acc[i][2] + bv.z;
        o.w = acc[i][3] + bv.w;
        if (relu) {
            o.x = o.x > 0.f ? o.x : 0.f;
            o.y = o.y > 0.f ? o.y : 0.f;
            o.z = o.z > 0.f ? o.z : 0.f;
            o.w = o.w > 0.f ? o.w : 0.f;
        }
        *(float4*)(C + (size_t)row * Nc + c0 + tx * 4) = o;
    }
}

// ---------------------------------------------------------------------------
// K3: relation-aware flash attention.
// Grid (8 n-chunks, H, B), 256 threads. Thread t: q-row r=t&63 of the chunk,
// m-slice s=t>>6 (16 of every 64 m per tile). Online softmax; 4-slice combine.
__global__ __launch_bounds__(256) void attn_kernel(
    const float* __restrict__ qkv,       // [BN, 768] (q|k|v)
    const int* __restrict__ relations,   // [B,N,N]
    const void* __restrict__ mask,
    const int* __restrict__ flag,        // 1 = byte mask, 0 = int mask
    const float* __restrict__ relk_g,    // [100,32]
    const float* __restrict__ relv_g,
    float* __restrict__ zout)            // [BN, 256]
{
    const int b = blockIdx.z, h = blockIdx.y, n0 = blockIdx.x * 64;
    const int t = threadIdx.x;
    const int r = t & 63, s = t >> 6;

    __shared__ float relk[100][33];
    __shared__ float relv[100][33];
    __shared__ union {
        struct {
            int   rel_t[64][65];
            float k_t[64][36];
            float v_t[64][36];
        } a;
        float comb[64][4][34];
    } u;

    const bool mbyte = (*flag != 0);
    const unsigned char* m8 = (const unsigned char*)mask;
    const int* m32 = (const int*)mask;

    for (int i = t; i < 3200; i += 256) {
        int rr = i >> 5, j = i & 31;
        relk[rr][j] = relk_g[i];
        relv[rr][j] = relv_g[i];
    }

    // q row (pre-scaled by 1/sqrt(dh))
    float qreg[32];
    const float scale = 0.17677669529663687f;
    {
        size_t qbase = ((size_t)(b * NN + n0 + r)) * 768 + h * 32;
#pragma unroll
        for (int j4 = 0; j4 < 8; ++j4) {
            float4 qv = *(const float4*)(qkv + qbase + j4 * 4);
            qreg[j4 * 4 + 0] = qv.x * scale;
            qreg[j4 * 4 + 1] = qv.y * scale;
            qreg[j4 * 4 + 2] = qv.z * scale;
            qreg[j4 * 4 + 3] = qv.w * scale;
        }
    }

    float mx = -1e30f, sm = 0.f;
    float z[32];
#pragma unroll
    for (int j = 0; j < 32; ++j) z[j] = 0.f;

    for (int mt = 0; mt < 8; ++mt) {
        __syncthreads();
        // stage relations + mask (mask folded as rel=-1)
        for (int i = t; i < 4096; i += 256) {
            int rr = i >> 6, mm = i & 63;
            size_t gi = ((size_t)(b * NN + n0 + rr)) * NN + mt * 64 + mm;
            int rel = relations[gi];
            int ok = mbyte ? (int)m8[gi] : (int)(m32[gi] != 0);
            u.a.rel_t[rr][mm] = ok ? rel : -1;
        }
        // stage k/v tiles [64][32] (float4)
        for (int i = t; i < 512; i += 256) {
            int mm = i >> 3, j4 = (i & 7) * 4;
            size_t kb = ((size_t)(b * NN + mt * 64 + mm)) * 768 + h * 32 + j4;
            *(float4*)&u.a.k_t[mm][j4] = *(const float4*)(qkv + kb + 256);
            *(float4*)&u.a.v_t[mm][j4] = *(const float4*)(qkv + kb + 512);
        }
        __syncthreads();
#pragma unroll 4
        for (int i = 0; i < 16; ++i) {
            int mm = s * 16 + i;
            int rel = u.a.rel_t[r][mm];
            if (rel < 0) continue;
            float sc = 0.f;
#pragma unroll
            for (int j = 0; j < 32; ++j)
                sc += qreg[j] * (u.a.k_t[mm][j] + relk[rel][j]);
            if (sc > mx) {
                float wt = __expf(mx - sc);
                sm *= wt;
#pragma unroll
                for (int j = 0; j < 32; ++j) z[j] *= wt;
                mx = sc;
            }
            float p = __expf(sc - mx);
            sm += p;
#pragma unroll
            for (int j = 0; j < 32; ++j)
                z[j] += p * (u.a.v_t[mm][j] + relv[rel][j]);
        }
    }
    __syncthreads();
    u.comb[r][s][0] = mx;
    u.comb[r][s][1] = sm;
#pragma unroll
    for (int j = 0; j < 32; ++j) u.comb[r][s][2 + j] = z[j];
    __syncthreads();

    // combine 4 slices; thread t handles (row t>>2, 8 cols)
    {
        int row2 = t >> 2, part = t & 3;
        float m0 = u.comb[row2][0][0], m1 = u.comb[row2][1][0];
        float m2 = u.comb[row2][2][0], m3 = u.comb[row2][3][0];
        float M = fmaxf(fmaxf(m0, m1), fmaxf(m2, m3));
        float e0 = __expf(m0 - M), e1 = __expf(m1 - M);
        float e2 = __expf(m2 - M), e3 = __expf(m3 - M);
        float SM = u.comb[row2][0][1] * e0 + u.comb[row2][1][1] * e1 +
                   u.comb[row2][2][1] * e2 + u.comb[row2][3][1] * e3;
        float inv = 1.f / SM;
        size_t ob = ((size_t)(b * NN + n0 + row2)) * 256 + h * 32 + part * 8;
#pragma unroll
        for (int j = 0; j < 8; ++j) {
            int jj = part * 8 + j;
            float accv = u.comb[row2][0][2 + jj] * e0 + u.comb[row2][1][2 + jj] * e1 +
                         u.comb[row2][2][2 + jj] * e2 + u.comb[row2][3][2 + jj] * e3;
            zout[ob + j] = accv * inv;
        }
    }
}

// ---------------------------------------------------------------------------
// K4: x = LayerNorm(xin + y) * g + b   (wave per row, 4 rows/block)
__global__ __launch_bounds__(256) void ln_kernel(
    const float* __restrict__ xin, const float* __restrict__ y,
    const float* __restrict__ g, const float* __restrict__ bsh,
    float* __restrict__ xout)
{
    const int t = threadIdx.x;
    const int w = t >> 6, lane = t & 63;
    const size_t row = (size_t)blockIdx.x * 4 + w;
    const float4 xv = *(const float4*)(xin + row * 256 + lane * 4);
    const float4 yv = *(const float4*)(y + row * 256 + lane * 4);
    float4 sv;
    sv.x = xv.x + yv.x; sv.y = xv.y + yv.y; sv.z = xv.z + yv.z; sv.w = xv.w + yv.w;
    float sum = sv.x + sv.y + sv.z + sv.w;
    float sq  = sv.x * sv.x + sv.y * sv.y + sv.z * sv.z + sv.w * sv.w;
#pragma unroll
    for (int off = 1; off < 64; off <<= 1) {
        sum += __shfl_xor(sum, off, 64);
        sq  += __shfl_xor(sq, off, 64);
    }
    const float mu = sum * (1.f / 256.f);
    const float var = sq * (1.f / 256.f) - mu * mu;
    const float rs = rsqrtf(var + 1e-5f);
    const float4 gv = *(const float4*)(g + lane * 4);
    const float4 bv = *(const float4*)(bsh + lane * 4);
    float4 o;
    o.x = (sv.x - mu) * rs * gv.x + bv.x;
    o.y = (sv.y - mu) * rs * gv.y + bv.y;
    o.z = (sv.z - mu) * rs * gv.z + bv.z;
    o.w = (sv.w - mu) * rs * gv.w + bv.w;
    *(float4*)(xout + row * 256 + lane * 4) = o;
}

// ---------------------------------------------------------------------------
extern "C" void kernel_launch(void* const* d_in, const int* in_sizes, int n_in,
                              void* d_out, int out_size, void* d_ws, size_t ws_size,
                              hipStream_t stream)
{
    (void)in_sizes; (void)n_in; (void)out_size; (void)ws_size;
    const int*   tok   = (const int*)d_in[0];
    const int*   rel   = (const int*)d_in[1];
    const void*  mask  = d_in[2];
    const float* embed = (const float*)d_in[3];
    const float* W_in  = (const float*)d_in[4];
    const float* b_in  = (const float*)d_in[5];
    const float* Wq    = (const float*)d_in[6];
    const float* Wk    = (const float*)d_in[7];
    const float* Wv    = (const float*)d_in[8];
    const float* Wo    = (const float*)d_in[9];
    const float* ln1g  = (const float*)d_in[10];
    const float* ln1b  = (const float*)d_in[11];
    const float* ln2g  = (const float*)d_in[12];
    const float* ln2b  = (const float*)d_in[13];
    const float* W1    = (const float*)d_in[14];
    const float* b1    = (const float*)d_in[15];
    const float* W2    = (const float*)d_in[16];
    const float* b2    = (const float*)d_in[17];
    const float* relk  = (const float*)d_in[18];
    const float* relv  = (const float*)d_in[19];
    const float* Wout  = (const float*)d_in[20];
    const float* bout  = (const float*)d_in[21];
    float* out = (float*)d_out;

    float* ws  = (float*)d_ws;
    float* x   = ws;                       // 1M floats
    float* z   = ws + (1u << 20);          // 1M
    float* zo  = ws + 2u * (1u << 20);     // 1M
    float* qkv = ws + 3u * (1u << 20);     // 3M
    float* hb  = ws + 6u * (1u << 20);     // 4M
    int*   flag = (int*)(ws + 10u * (1u << 20));

    detect_mask_kernel<<<1, 256, 0, stream>>>((const unsigned char*)mask, flag);
    embed_proj_kernel<<<512, 256, 0, stream>>>(tok, embed, W_in, b_in, x);

    for (int l = 0; l < 4; ++l) {
        const float* wq = Wq + (size_t)l * 65536;
        const float* wk = Wk + (size_t)l * 65536;
        const float* wv = Wv + (size_t)l * 65536;
        const float* wo = Wo + (size_t)l * 65536;
        const float* w1 = W1 + (size_t)l * 262144;
        const float* w2 = W2 + (size_t)l * 262144;

        // fused QKV: [4096,256] @ 3x[256,256] -> qkv [4096,768]
        gemm_kernel<<<dim3(12, 32), 256, 0, stream>>>(x, wq, wk, wv, 256, nullptr,
                                                      qkv, NTOK, 256, 768, 0);
        attn_kernel<<<dim3(8, 8, 8), 256, 0, stream>>>(qkv, rel, mask, flag,
                                                       relk, relv, z);
        gemm_kernel<<<dim3(4, 32), 256, 0, stream>>>(z, wo, wo, wo, 256, nullptr,
                                                     zo, NTOK, 256, 256, 0);
        ln_kernel<<<1024, 256, 0, stream>>>(x, zo, ln1g + l * 256, ln1b + l * 256, x);
        gemm_kernel<<<dim3(16, 32), 256, 0, stream>>>(x, w1, w1, w1, 1024, b1 + l * 1024,
                                                      hb, NTOK, 256, 1024, 1);
        gemm_kernel<<<dim3(4, 32), 256, 0, stream>>>(hb, w2, w2, w2, 256, b2 + l * 256,
                                                     zo, NTOK, 1024, 256, 0);
        ln_kernel<<<1024, 256, 0, stream>>>(x, zo, ln2g + l * 256, ln2b + l * 256, x);
    }
    gemm_kernel<<<dim3(4, 32), 256, 0, stream>>>(x, Wout, Wout, Wout, 256, bout,
                                                 out, NTOK, 256, 256, 0);
}

// Round 2
// 1623.167 us; speedup vs baseline: 1.0809x; 1.0809x over previous
//
#include <hip/hip_runtime.h>
#include <hip/hip_bf16.h>

#define NTOK 4096   // B*N
#define NN   512
#define DD   256

__device__ __forceinline__ float bf16_to_f(unsigned short u) {
    unsigned int x = ((unsigned int)u) << 16;
    return __builtin_bit_cast(float, x);
}
__device__ __forceinline__ unsigned short f_to_bf16(float f) {
    unsigned int b = __builtin_bit_cast(unsigned int, f);
    return (unsigned short)((b + 0x8000u) >> 16);
}

// ---------------------------------------------------------------------------
// K0: detect whether relations_mask is 1-byte bool or 4-byte int.
__global__ void detect_mask_kernel(const unsigned char* __restrict__ m, int* __restrict__ flag) {
    __shared__ int f;
    if (threadIdx.x == 0) f = 0;
    __syncthreads();
    int any = 0;
    for (int i = threadIdx.x; i < 4096; i += 256) {
        if ((i & 3) != 0 && m[i] != 0) any = 1;
    }
    if (any) atomicOr(&f, 1);
    __syncthreads();
    if (threadIdx.x == 0) *flag = f;   // 1 => byte mask, 0 => int32 mask
}

// ---------------------------------------------------------------------------
// K1: x[row,d] = relu(sum_e embed[tok[row]][e] * W_in[e][d] + b_in[d])
__global__ __launch_bounds__(256) void embed_proj_kernel(
    const int* __restrict__ tok, const float* __restrict__ embed,
    const float* __restrict__ W_in, const float* __restrict__ b_in,
    float* __restrict__ x)
{
    __shared__ float emb[8][304];
    __shared__ int tloc[8];
    const int t = threadIdx.x;
    const int r0 = blockIdx.x * 8;
    if (t < 8) tloc[t] = tok[r0 + t];
    __syncthreads();
    for (int i = t; i < 8 * 300; i += 256) {
        int r = i / 300, e = i - r * 300;
        emb[r][e] = embed[(size_t)tloc[r] * 300 + e];
    }
    __syncthreads();
    float acc[8] = {0.f,0.f,0.f,0.f,0.f,0.f,0.f,0.f};
    const int d = t;
    for (int e = 0; e < 300; ++e) {
        float w = W_in[e * 256 + d];
#pragma unroll
        for (int r = 0; r < 8; ++r) acc[r] += emb[r][e] * w;
    }
    const float bb = b_in[d];
#pragma unroll
    for (int r = 0; r < 8; ++r) {
        float o = acc[r] + bb;
        o = o > 0.f ? o : 0.f;
        x[(size_t)(r0 + r) * 256 + d] = o;
    }
}

// ---------------------------------------------------------------------------
// K2: generic fp32 GEMM  C[M,Nc] = act(A[M,K] @ W + bias)
__global__ __launch_bounds__(256) void gemm_kernel(
    const float* __restrict__ A,
    const float* __restrict__ W0, const float* __restrict__ W1p, const float* __restrict__ W2p,
    int ncPerW,
    const float* __restrict__ bias,
    float* __restrict__ C, int M, int K, int Nc, int relu)
{
    const int t = threadIdx.x;
    const int bn = blockIdx.x, bm = blockIdx.y;
    const int r0 = bm * 128, c0 = bn * 64;

    const float* W = W0;
    int cW = c0;
    if (c0 >= 2 * ncPerW)      { W = W2p; cW = c0 - 2 * ncPerW; }
    else if (c0 >= ncPerW)     { W = W1p; cW = c0 - ncPerW; }

    __shared__ float As[16][132];
    __shared__ float Ws[16][68];

    const int tx = t & 15, ty = t >> 4;
    float acc[8][4];
#pragma unroll
    for (int i = 0; i < 8; ++i)
#pragma unroll
        for (int j = 0; j < 4; ++j) acc[i][j] = 0.f;

    for (int k0 = 0; k0 < K; k0 += 16) {
#pragma unroll
        for (int ii = 0; ii < 2; ++ii) {
            int f4 = t * 2 + ii;
            int row = f4 >> 2;
            int kk4 = (f4 & 3) * 4;
            const float4 av = *(const float4*)(A + (size_t)(r0 + row) * K + k0 + kk4);
            As[kk4 + 0][row] = av.x;
            As[kk4 + 1][row] = av.y;
            As[kk4 + 2][row] = av.z;
            As[kk4 + 3][row] = av.w;
        }
        {
            int kk = t >> 4, c4 = (t & 15) * 4;
            const float4 wv = *(const float4*)(W + (size_t)(k0 + kk) * ncPerW + cW + c4);
            *(float4*)&Ws[kk][c4] = wv;
        }
        __syncthreads();
#pragma unroll
        for (int kk = 0; kk < 16; ++kk) {
            float4 wv = *(const float4*)&Ws[kk][tx * 4];
            float4 a0 = *(const float4*)&As[kk][ty * 8];
            float4 a1 = *(const float4*)&As[kk][ty * 8 + 4];
            float ar[8] = {a0.x, a0.y, a0.z, a0.w, a1.x, a1.y, a1.z, a1.w};
            float wr[4] = {wv.x, wv.y, wv.z, wv.w};
#pragma unroll
            for (int i = 0; i < 8; ++i)
#pragma unroll
                for (int j = 0; j < 4; ++j) acc[i][j] += ar[i] * wr[j];
        }
        __syncthreads();
    }
    float4 bv = make_float4(0.f, 0.f, 0.f, 0.f);
    if (bias) bv = *(const float4*)(bias + c0 + tx * 4);
#pragma unroll
    for (int i = 0; i < 8; ++i) {
        int row = r0 + ty * 8 + i;
        float4 o;
        o.x = acc[i][0] + bv.x;
        o.y = acc[i][1] + bv.y;
        o.z = acc[i][2] + bv.z;
        o.w = acc[i][3] + bv.w;
        if (relu) {
            o.x = o.x > 0.f ? o.x : 0.f;
            o.y = o.y > 0.f ? o.y : 0.f;
            o.z = o.z > 0.f ? o.z : 0.f;
            o.w = o.w > 0.f ? o.w : 0.f;
        }
        *(float4*)(C + (size_t)row * Nc + c0 + tx * 4) = o;
    }
}

// ---------------------------------------------------------------------------
// K3: relation-aware attention, restructured (RAT-SQL factorization):
//   score = q.k + qrk[r][rel]          (qrk precomputed per row x 100 rels)
//   z     = sum_m p*v  +  sum_rel wrel[rel]*relv[rel]   (wrel[r][rel] += p)
// No online max: scores are O(1) for this model; exp clamped at 50 for safety.
// Grid (8 chunks, H, B), 256 thr: r=t&63 (q-row), s=t>>6 (m-slice).
__global__ __launch_bounds__(256) void attn_kernel(
    const float* __restrict__ qkv,       // [BN, 768] (q|k|v)
    const int* __restrict__ relations,   // [B,N,N]
    const void* __restrict__ mask,
    const int* __restrict__ flag,        // 1 = byte mask, 0 = int mask
    const float* __restrict__ relk_g,    // [100,32]
    const float* __restrict__ relv_g,
    float* __restrict__ zout)            // [BN, 256]
{
    const int b = blockIdx.z, h = blockIdx.y, n0 = blockIdx.x * 64;
    const int t = threadIdx.x;
    const int r = t & 63, s = t >> 6;

    __shared__ float wrel[64][100];                    // 25600 B, persistent
    __shared__ union {
        unsigned short qrk_h[64][102];                 // phases B..C (13056 B)
        float comb[64][37];                            // phase E (9472 B)
    } uq;
    __shared__ union {
        float relx[100][36];                           // relk (A/B) or relv (D/E)
        struct { float k_t[64][36]; float v_t[64][36]; } kv;   // phase C (18432 B)
    } um;
    __shared__ short rel_t[64][66];                    // 8448 B, phase C

    const bool mbyte = (*flag != 0);
    const unsigned char* m8 = (const unsigned char*)mask;
    const int* m32 = (const int*)mask;

    // Phase A: zero wrel, stage relk, load q row (pre-scaled).
    for (int i = t; i < 6400; i += 256) ((float*)wrel)[i] = 0.f;
    for (int i = t; i < 800; i += 256) {
        int row = i >> 3, q4 = (i & 7) << 2;
        *(float4*)&um.relx[row][q4] = *(const float4*)(relk_g + row * 32 + q4);
    }
    float qreg[32];
    const float scale = 0.17677669529663687f;
    {
        size_t qbase = ((size_t)(b * NN + n0 + r)) * 768 + h * 32;
#pragma unroll
        for (int j4 = 0; j4 < 8; ++j4) {
            float4 qv = *(const float4*)(qkv + qbase + j4 * 4);
            qreg[j4 * 4 + 0] = qv.x * scale;
            qreg[j4 * 4 + 1] = qv.y * scale;
            qreg[j4 * 4 + 2] = qv.z * scale;
            qreg[j4 * 4 + 3] = qv.w * scale;
        }
    }
    __syncthreads();

    // Phase B: qrk[r][rel] = q_r . relk[rel]  (25 rels per slice, broadcast reads)
    for (int rel = s * 25; rel < s * 25 + 25; ++rel) {
        float d = 0.f;
#pragma unroll
        for (int j = 0; j < 32; ++j) d += qreg[j] * um.relx[rel][j];
        uq.qrk_h[r][rel] = f_to_bf16(d);
    }

    float sm = 0.f;
    float z[32];
#pragma unroll
    for (int j = 0; j < 32; ++j) z[j] = 0.f;

    // Phase C: main loop over 8 m-tiles of 64
    for (int mt = 0; mt < 8; ++mt) {
        __syncthreads();
        for (int i = t; i < 4096; i += 256) {
            int rr = i >> 6, mm = i & 63;
            size_t gi = ((size_t)(b * NN + n0 + rr)) * NN + mt * 64 + mm;
            int rl = relations[gi];
            int ok = mbyte ? (int)m8[gi] : (int)(m32[gi] != 0);
            rel_t[rr][mm] = ok ? (short)rl : (short)-1;
        }
        for (int i = t; i < 512; i += 256) {
            int mm = i >> 3, j4 = (i & 7) * 4;
            size_t kb = ((size_t)(b * NN + mt * 64 + mm)) * 768 + h * 32 + j4;
            *(float4*)&um.kv.k_t[mm][j4] = *(const float4*)(qkv + kb + 256);
            *(float4*)&um.kv.v_t[mm][j4] = *(const float4*)(qkv + kb + 512);
        }
        __syncthreads();
#pragma unroll 4
        for (int i = 0; i < 16; ++i) {
            int mm = s * 16 + i;
            int rel = rel_t[r][mm];
            if (rel < 0) continue;
            float sc = 0.f;
#pragma unroll
            for (int j = 0; j < 32; ++j) sc += qreg[j] * um.kv.k_t[mm][j];
            sc += bf16_to_f(uq.qrk_h[r][rel]);
            float p = __expf(fminf(sc, 50.f));
            sm += p;
#pragma unroll
            for (int j = 0; j < 32; ++j) z[j] += p * um.kv.v_t[mm][j];
            atomicAdd(&wrel[r][rel], p);
        }
    }

    // Phase D: stage relv, zero comb
    __syncthreads();
    for (int i = t; i < 800; i += 256) {
        int row = i >> 3, q4 = (i & 7) << 2;
        *(float4*)&um.relx[row][q4] = *(const float4*)(relv_g + row * 32 + q4);
    }
    for (int i = t; i < 64 * 37; i += 256) ((float*)uq.comb)[i] = 0.f;
    __syncthreads();

    // Phase E1: combine the 4 m-slices through LDS atomics
#pragma unroll
    for (int j = 0; j < 32; ++j) atomicAdd(&uq.comb[r][j], z[j]);
    atomicAdd(&uq.comb[r][32], sm);
    __syncthreads();

    // Phase E2: add relation-value term and normalize. thread -> (row, 8 cols)
    {
        int row = t >> 2, part = t & 3;
        float inv = 1.f / uq.comb[row][32];
        float acc[8];
#pragma unroll
        for (int j = 0; j < 8; ++j) acc[j] = uq.comb[row][part * 8 + j];
        for (int rel = 0; rel < 100; ++rel) {
            float w = wrel[row][rel];
#pragma unroll
            for (int j = 0; j < 8; ++j) acc[j] += w * um.relx[rel][part * 8 + j];
        }
        size_t ob = ((size_t)(b * NN + n0 + row)) * 256 + h * 32 + part * 8;
#pragma unroll
        for (int j = 0; j < 8; ++j) zout[ob + j] = acc[j] * inv;
    }
}

// ---------------------------------------------------------------------------
// K4: x = LayerNorm(xin + y) * g + b
__global__ __launch_bounds__(256) void ln_kernel(
    const float* __restrict__ xin, const float* __restrict__ y,
    const float* __restrict__ g, const float* __restrict__ bsh,
    float* __restrict__ xout)
{
    const int t = threadIdx.x;
    const int w = t >> 6, lane = t & 63;
    const size_t row = (size_t)blockIdx.x * 4 + w;
    const float4 xv = *(const float4*)(xin + row * 256 + lane * 4);
    const float4 yv = *(const float4*)(y + row * 256 + lane * 4);
    float4 sv;
    sv.x = xv.x + yv.x; sv.y = xv.y + yv.y; sv.z = xv.z + yv.z; sv.w = xv.w + yv.w;
    float sum = sv.x + sv.y + sv.z + sv.w;
    float sq  = sv.x * sv.x + sv.y * sv.y + sv.z * sv.z + sv.w * sv.w;
#pragma unroll
    for (int off = 1; off < 64; off <<= 1) {
        sum += __shfl_xor(sum, off, 64);
        sq  += __shfl_xor(sq, off, 64);
    }
    const float mu = sum * (1.f / 256.f);
    const float var = sq * (1.f / 256.f) - mu * mu;
    const float rs = rsqrtf(var + 1e-5f);
    const float4 gv = *(const float4*)(g + lane * 4);
    const float4 bv = *(const float4*)(bsh + lane * 4);
    float4 o;
    o.x = (sv.x - mu) * rs * gv.x + bv.x;
    o.y = (sv.y - mu) * rs * gv.y + bv.y;
    o.z = (sv.z - mu) * rs * gv.z + bv.z;
    o.w = (sv.w - mu) * rs * gv.w + bv.w;
    *(float4*)(xout + row * 256 + lane * 4) = o;
}

// ---------------------------------------------------------------------------
extern "C" void kernel_launch(void* const* d_in, const int* in_sizes, int n_in,
                              void* d_out, int out_size, void* d_ws, size_t ws_size,
                              hipStream_t stream)
{
    (void)in_sizes; (void)n_in; (void)out_size; (void)ws_size;
    const int*   tok   = (const int*)d_in[0];
    const int*   rel   = (const int*)d_in[1];
    const void*  mask  = d_in[2];
    const float* embed = (const float*)d_in[3];
    const float* W_in  = (const float*)d_in[4];
    const float* b_in  = (const float*)d_in[5];
    const float* Wq    = (const float*)d_in[6];
    const float* Wk    = (const float*)d_in[7];
    const float* Wv    = (const float*)d_in[8];
    const float* Wo    = (const float*)d_in[9];
    const float* ln1g  = (const float*)d_in[10];
    const float* ln1b  = (const float*)d_in[11];
    const float* ln2g  = (const float*)d_in[12];
    const float* ln2b  = (const float*)d_in[13];
    const float* W1    = (const float*)d_in[14];
    const float* b1    = (const float*)d_in[15];
    const float* W2    = (const float*)d_in[16];
    const float* b2    = (const float*)d_in[17];
    const float* relk  = (const float*)d_in[18];
    const float* relv  = (const float*)d_in[19];
    const float* Wout  = (const float*)d_in[20];
    const float* bout  = (const float*)d_in[21];
    float* out = (float*)d_out;

    float* ws  = (float*)d_ws;
    float* x   = ws;                       // 1M floats
    float* z   = ws + (1u << 20);          // 1M
    float* zo  = ws + 2u * (1u << 20);     // 1M
    float* qkv = ws + 3u * (1u << 20);     // 3M
    float* hb  = ws + 6u * (1u << 20);     // 4M
    int*   flag = (int*)(ws + 10u * (1u << 20));

    detect_mask_kernel<<<1, 256, 0, stream>>>((const unsigned char*)mask, flag);
    embed_proj_kernel<<<512, 256, 0, stream>>>(tok, embed, W_in, b_in, x);

    for (int l = 0; l < 4; ++l) {
        const float* wq = Wq + (size_t)l * 65536;
        const float* wk = Wk + (size_t)l * 65536;
        const float* wv = Wv + (size_t)l * 65536;
        const float* wo = Wo + (size_t)l * 65536;
        const float* w1 = W1 + (size_t)l * 262144;
        const float* w2 = W2 + (size_t)l * 262144;

        gemm_kernel<<<dim3(12, 32), 256, 0, stream>>>(x, wq, wk, wv, 256, nullptr,
                                                      qkv, NTOK, 256, 768, 0);
        attn_kernel<<<dim3(8, 8, 8), 256, 0, stream>>>(qkv, rel, mask, flag,
                                                       relk, relv, z);
        gemm_kernel<<<dim3(4, 32), 256, 0, stream>>>(z, wo, wo, wo, 256, nullptr,
                                                     zo, NTOK, 256, 256, 0);
        ln_kernel<<<1024, 256, 0, stream>>>(x, zo, ln1g + l * 256, ln1b + l * 256, x);
        gemm_kernel<<<dim3(16, 32), 256, 0, stream>>>(x, w1, w1, w1, 1024, b1 + l * 1024,
                                                      hb, NTOK, 256, 1024, 1);
        gemm_kernel<<<dim3(4, 32), 256, 0, stream>>>(hb, w2, w2, w2, 256, b2 + l * 256,
                                                     zo, NTOK, 1024, 256, 0);
        ln_kernel<<<1024, 256, 0, stream>>>(x, zo, ln2g + l * 256, ln2b + l * 256, x);
    }
    gemm_kernel<<<dim3(4, 32), 256, 0, stream>>>(x, Wout, Wout, Wout, 256, bout,
                                                 out, NTOK, 256, 256, 0);
}

// Round 3
// 788.759 us; speedup vs baseline: 2.2243x; 2.0579x over previous
//
#include <hip/hip_runtime.h>
#include <hip/hip_bf16.h>

#define NTOK 4096   // B*N
#define NN   512

typedef __attribute__((ext_vector_type(8))) short bf16x8;
typedef __attribute__((ext_vector_type(4))) short bf16x4;
typedef __attribute__((ext_vector_type(4))) float f32x4;

__device__ __forceinline__ float bf16_to_f(unsigned short u) {
    unsigned int x = ((unsigned int)u) << 16;
    return __builtin_bit_cast(float, x);
}
__device__ __forceinline__ unsigned short f_to_bf16(float f) {
    unsigned int b = __builtin_bit_cast(unsigned int, f);
    return (unsigned short)((b + 0x7fff + ((b >> 16) & 1)) >> 16);
}
__device__ __forceinline__ bf16x8 pack8(float4 a, float4 b) {
    bf16x8 v;
    v[0]=(short)f_to_bf16(a.x); v[1]=(short)f_to_bf16(a.y);
    v[2]=(short)f_to_bf16(a.z); v[3]=(short)f_to_bf16(a.w);
    v[4]=(short)f_to_bf16(b.x); v[5]=(short)f_to_bf16(b.y);
    v[6]=(short)f_to_bf16(b.z); v[7]=(short)f_to_bf16(b.w);
    return v;
}

// ---------------------------------------------------------------------------
// K0: detect whether relations_mask is 1-byte bool or 4-byte int.
__global__ void detect_mask_kernel(const unsigned char* __restrict__ m, int* __restrict__ flag) {
    __shared__ int f;
    if (threadIdx.x == 0) f = 0;
    __syncthreads();
    int any = 0;
    for (int i = threadIdx.x; i < 4096; i += 256) {
        if ((i & 3) != 0 && m[i] != 0) any = 1;
    }
    if (any) atomicOr(&f, 1);
    __syncthreads();
    if (threadIdx.x == 0) *flag = f;   // 1 => byte mask, 0 => int32 mask
}

// ---------------------------------------------------------------------------
// K1: x[row,d] = relu(sum_e embed[tok[row]][e] * W_in[e][d] + b_in[d])
__global__ __launch_bounds__(256) void embed_proj_kernel(
    const int* __restrict__ tok, const float* __restrict__ embed,
    const float* __restrict__ W_in, const float* __restrict__ b_in,
    float* __restrict__ x)
{
    __shared__ float emb[8][304];
    __shared__ int tloc[8];
    const int t = threadIdx.x;
    const int r0 = blockIdx.x * 8;
    if (t < 8) tloc[t] = tok[r0 + t];
    __syncthreads();
    for (int i = t; i < 8 * 300; i += 256) {
        int r = i / 300, e = i - r * 300;
        emb[r][e] = embed[(size_t)tloc[r] * 300 + e];
    }
    __syncthreads();
    float acc[8] = {0.f,0.f,0.f,0.f,0.f,0.f,0.f,0.f};
    const int d = t;
    for (int e = 0; e < 300; ++e) {
        float w = W_in[e * 256 + d];
#pragma unroll
        for (int r = 0; r < 8; ++r) acc[r] += emb[r][e] * w;
    }
    const float bb = b_in[d];
#pragma unroll
    for (int r = 0; r < 8; ++r) {
        float o = acc[r] + bb;
        o = o > 0.f ? o : 0.f;
        x[(size_t)(r0 + r) * 256 + d] = o;
    }
}

// ---------------------------------------------------------------------------
// K2: MFMA bf16 GEMM  C[M,Nc] = act(A[M,K] @ W + bias), fp32 in/out.
// BM=BN=64, BK=32, 256 threads = 4 waves; wave w -> rows 16w..16w+15, all 64 cols.
// W split across up to 3 matrices of ncPerW columns (fused QKV).
__global__ __launch_bounds__(256) void gemm_mfma(
    const float* __restrict__ A,
    const float* __restrict__ W0, const float* __restrict__ W1p, const float* __restrict__ W2p,
    int ncPerW, const float* __restrict__ bias,
    float* __restrict__ C, int M, int K, int Nc, int relu)
{
    __shared__ unsigned short As[64][40];   // [row][k], pad 40 (80B stride, 16B-aligned)
    __shared__ unsigned short Bs[64][40];   // [col][k] = W^T tile

    const int t = threadIdx.x;
    const int lane = t & 63, w = t >> 6;
    const int g = lane >> 4, li = lane & 15;
    const int r0 = blockIdx.y * 64, c0 = blockIdx.x * 64;

    const float* Wp = W0; int cW = c0;
    if (c0 >= 2 * ncPerW)      { Wp = W2p; cW = c0 - 2 * ncPerW; }
    else if (c0 >= ncPerW)     { Wp = W1p; cW = c0 - ncPerW; }

    f32x4 acc[4];
#pragma unroll
    for (int i = 0; i < 4; ++i) acc[i] = (f32x4){0.f, 0.f, 0.f, 0.f};

    const int arow = t >> 2, ad8 = (t & 3) * 8;   // A staging: 64 rows x 4 thr x 8 k
    const int bnn = t & 63, bk8 = (t >> 6) * 8;   // B staging: 64 cols x 4 k-groups

    for (int k0 = 0; k0 < K; k0 += 32) {
        __syncthreads();
        {   // A tile [64][32] f32 -> bf16
            const float* ap = A + (size_t)(r0 + arow) * K + k0 + ad8;
            float4 a0 = *(const float4*)ap;
            float4 a1 = *(const float4*)(ap + 4);
            *(bf16x8*)&As[arow][ad8] = pack8(a0, a1);
        }
        {   // B tile transposed: Bs[n][k] = W[k0+k][cW+n]
            bf16x8 v;
#pragma unroll
            for (int j = 0; j < 8; ++j) {
                float xv = Wp[(size_t)(k0 + bk8 + j) * ncPerW + cW + bnn];
                v[j] = (short)f_to_bf16(xv);
            }
            *(bf16x8*)&Bs[bnn][bk8] = v;
        }
        __syncthreads();
        bf16x8 af = *(const bf16x8*)&As[16 * w + li][g * 8];
#pragma unroll
        for (int sub = 0; sub < 4; ++sub) {
            bf16x8 bfr = *(const bf16x8*)&Bs[16 * sub + li][g * 8];
            acc[sub] = __builtin_amdgcn_mfma_f32_16x16x32_bf16(af, bfr, acc[sub], 0, 0, 0);
        }
    }
#pragma unroll
    for (int sub = 0; sub < 4; ++sub) {
        int col = c0 + sub * 16 + li;
        float bv = bias ? bias[col] : 0.f;
#pragma unroll
        for (int r = 0; r < 4; ++r) {
            int row = r0 + 16 * w + g * 4 + r;
            float o = acc[sub][r] + bv;
            if (relu) o = fmaxf(o, 0.f);
            C[(size_t)row * Nc + col] = o;
        }
    }
}

// ---------------------------------------------------------------------------
// K3: relation-aware attention via MFMA.
// Block = (b, h, 64-q-chunk); 4 waves, wave w owns q-rows 16w..16w+15.
//  qrk[q][rel] = (q*scale).relk[rel]     (MFMA, 7 chunks)
//  S = Q@K^T (MFMA) + qrk gather; p = exp(S) (no max-sub: scores are O(1))
//  wrel[q][rel] += p (LDS atomic scatter); z = P@V (MFMA) + W@relv (MFMA); z /= sum p
__global__ __launch_bounds__(256) void attn_mfma(
    const float* __restrict__ qkv,       // [BN, 768] (q|k|v)
    const int* __restrict__ relations,   // [B,N,N]
    const void* __restrict__ mask,
    const int* __restrict__ flag,        // 1 = byte mask, 0 = int mask
    const float* __restrict__ relk_g,    // [100,32]
    const float* __restrict__ relv_g,
    float* __restrict__ zout)            // [BN, 256]
{
    const int b = blockIdx.z, h = blockIdx.y, n0 = blockIdx.x * 64;
    const int t = threadIdx.x;
    const int lane = t & 63, w = t >> 6;
    const int g = lane >> 4, li = lane & 15;

    __shared__ float wrel[64][100];            // 25600 B
    __shared__ unsigned short qrk[64][100];    // 12800 B
    __shared__ union {
        unsigned short relk_s[112][40];        // 8960 B (rows >=100: garbage, discarded)
        unsigned short relvT[32][136];         // 8704 B ([d][rel], rel>=100 zeroed)
    } ru;
    __shared__ unsigned short k_t[32][40];     // 2560 B  [m][d]
    __shared__ unsigned short v_t[32][40];     // 2560 B  [d][m] (transposed)
    __shared__ unsigned short p_s[4][16][40];  // 5120 B  per-wave P tile [q][m]
    // total 57600 B

    const bool mbyte = (*flag != 0);
    const unsigned char* m8 = (const unsigned char*)mask;
    const int* m32 = (const int*)mask;

    // ---- Phase A: zero wrel, stage relk (bf16, natural [rel][d]), load Q frag
    for (int i = t; i < 6400; i += 256) ((float*)wrel)[i] = 0.f;
    for (int i = t; i < 400; i += 256) {
        int rr = i >> 2, d8 = (i & 3) * 8;
        const float* sp = relk_g + rr * 32 + d8;
        *(bf16x8*)&ru.relk_s[rr][d8] = pack8(*(const float4*)sp, *(const float4*)(sp + 4));
    }
    const float scale = 0.17677669529663687f;
    bf16x8 qf;
    {
        const float* qp = qkv + (size_t)(b * NN + n0 + 16 * w + li) * 768 + h * 32 + g * 8;
        float4 q0 = *(const float4*)qp, q1 = *(const float4*)(qp + 4);
        q0.x *= scale; q0.y *= scale; q0.z *= scale; q0.w *= scale;
        q1.x *= scale; q1.y *= scale; q1.z *= scale; q1.w *= scale;
        qf = pack8(q0, q1);
    }
    __syncthreads();

    // ---- Phase B: qrk = Q @ relk^T  (cols = rel, 7 chunks of 16)
#pragma unroll
    for (int rc = 0; rc < 7; ++rc) {
        bf16x8 bb = *(const bf16x8*)&ru.relk_s[rc * 16 + li][g * 8];
        f32x4 s = __builtin_amdgcn_mfma_f32_16x16x32_bf16(qf, bb, (f32x4){0.f,0.f,0.f,0.f}, 0, 0, 0);
        int col = rc * 16 + li;
        if (col < 100) {
#pragma unroll
            for (int r = 0; r < 4; ++r)
                qrk[16 * w + g * 4 + r][col] = f_to_bf16(s[r]);
        }
    }
    __syncthreads();

    // ---- Phase B2: stage relv TRANSPOSED: relvT[d][rel]; zero rel 100..135
    for (int i = t; i < 32 * 36; i += 256) {
        int d = i / 36, c = 100 + (i - (i / 36) * 36);
        ru.relvT[d][c] = 0;
    }
    for (int i = t; i < 400; i += 256) {
        int rr = i >> 2, d8 = (i & 3) * 8;
        const float* sp = relv_g + rr * 32 + d8;
        float4 s0 = *(const float4*)sp, s1 = *(const float4*)(sp + 4);
        ru.relvT[d8 + 0][rr] = f_to_bf16(s0.x);
        ru.relvT[d8 + 1][rr] = f_to_bf16(s0.y);
        ru.relvT[d8 + 2][rr] = f_to_bf16(s0.z);
        ru.relvT[d8 + 3][rr] = f_to_bf16(s0.w);
        ru.relvT[d8 + 4][rr] = f_to_bf16(s1.x);
        ru.relvT[d8 + 5][rr] = f_to_bf16(s1.y);
        ru.relvT[d8 + 6][rr] = f_to_bf16(s1.z);
        ru.relvT[d8 + 7][rr] = f_to_bf16(s1.w);
    }
    __syncthreads();

    float smacc[4] = {0.f, 0.f, 0.f, 0.f};
    f32x4 zf[2];
    zf[0] = (f32x4){0.f,0.f,0.f,0.f};
    zf[1] = (f32x4){0.f,0.f,0.f,0.f};
    size_t rbase[4];
#pragma unroll
    for (int r = 0; r < 4; ++r)
        rbase[r] = ((size_t)(b * NN + n0 + 16 * w + g * 4 + r)) * NN;

    // ---- Main loop over 16 m-tiles of 32
    for (int mt = 0; mt < 16; ++mt) {
        const int m0 = mt * 32;
        __syncthreads();
        {   // stage K tile [32 m][32 d]
            int row = t >> 3, d4 = (t & 7) * 4;
            const float* kp = qkv + (size_t)(b * NN + m0 + row) * 768 + 256 + h * 32 + d4;
            float4 kv4 = *(const float4*)kp;
            bf16x4 kv;
            kv[0]=(short)f_to_bf16(kv4.x); kv[1]=(short)f_to_bf16(kv4.y);
            kv[2]=(short)f_to_bf16(kv4.z); kv[3]=(short)f_to_bf16(kv4.w);
            *(bf16x4*)&k_t[row][d4] = kv;
        }
        {   // stage V tile transposed [32 d][32 m]
            int m = t & 31, dg = t >> 5;
            const float* vp = qkv + (size_t)(b * NN + m0 + m) * 768 + 512 + h * 32 + dg * 4;
            float4 vv = *(const float4*)vp;
            v_t[dg * 4 + 0][m] = f_to_bf16(vv.x);
            v_t[dg * 4 + 1][m] = f_to_bf16(vv.y);
            v_t[dg * 4 + 2][m] = f_to_bf16(vv.z);
            v_t[dg * 4 + 3][m] = f_to_bf16(vv.w);
        }
        __syncthreads();
        // QK^T + score post-processing (2 chunks of 16 m)
#pragma unroll
        for (int c = 0; c < 2; ++c) {
            bf16x8 kf = *(const bf16x8*)&k_t[c * 16 + li][g * 8];
            f32x4 s = __builtin_amdgcn_mfma_f32_16x16x32_bf16(qf, kf, (f32x4){0.f,0.f,0.f,0.f}, 0, 0, 0);
            const int gm = m0 + c * 16 + li;
#pragma unroll
            for (int r = 0; r < 4; ++r) {
                const int ql = 16 * w + g * 4 + r;
                const size_t gi = rbase[r] + gm;
                int ok = mbyte ? (int)m8[gi] : (int)(m32[gi] != 0);
                float p = 0.f;
                if (ok) {
                    int rl = relations[gi];
                    float sc = s[r] + bf16_to_f(qrk[ql][rl]);
                    p = __expf(fminf(sc, 50.f));
                    atomicAdd(&wrel[ql][rl], p);
                }
                smacc[r] += p;
                p_s[w][g * 4 + r][c * 16 + li] = f_to_bf16(p);
            }
        }
        asm volatile("s_waitcnt lgkmcnt(0)" ::: "memory");
        // PV: z += P @ V
        bf16x8 pa = *(const bf16x8*)&p_s[w][li][g * 8];
#pragma unroll
        for (int dc = 0; dc < 2; ++dc) {
            bf16x8 vb = *(const bf16x8*)&v_t[dc * 16 + li][g * 8];
            zf[dc] = __builtin_amdgcn_mfma_f32_16x16x32_bf16(pa, vb, zf[dc], 0, 0, 0);
        }
    }
    __syncthreads();   // all wrel atomics complete

    // ---- Phase W: z += W @ relv  (K = rel, 4 chunks of 32, zero-guarded >=100)
#pragma unroll
    for (int kc = 0; kc < 4; ++kc) {
        const int kbase = kc * 32 + g * 8;
        const float* wp = &wrel[16 * w + li][0];
        bf16x8 af;
#pragma unroll
        for (int j = 0; j < 8; ++j) {
            int idx = kbase + j;
            float val = (idx < 100) ? wp[idx] : 0.f;
            af[j] = (short)f_to_bf16(val);
        }
#pragma unroll
        for (int dc = 0; dc < 2; ++dc) {
            bf16x8 vb = *(const bf16x8*)&ru.relvT[dc * 16 + li][kbase];
            zf[dc] = __builtin_amdgcn_mfma_f32_16x16x32_bf16(af, vb, zf[dc], 0, 0, 0);
        }
    }

    // ---- row sums (reduce across the 16 m-column lanes) and store
#pragma unroll
    for (int r = 0; r < 4; ++r) {
        smacc[r] += __shfl_xor(smacc[r], 1, 64);
        smacc[r] += __shfl_xor(smacc[r], 2, 64);
        smacc[r] += __shfl_xor(smacc[r], 4, 64);
        smacc[r] += __shfl_xor(smacc[r], 8, 64);
    }
#pragma unroll
    for (int r = 0; r < 4; ++r) {
        float inv = 1.f / smacc[r];
        size_t ob = ((size_t)(b * NN + n0 + 16 * w + g * 4 + r)) * 256 + h * 32;
#pragma unroll
        for (int dc = 0; dc < 2; ++dc)
            zout[ob + dc * 16 + li] = zf[dc][r] * inv;
    }
}

// ---------------------------------------------------------------------------
// K4: x = LayerNorm(xin + y) * g + b
__global__ __launch_bounds__(256) void ln_kernel(
    const float* __restrict__ xin, const float* __restrict__ y,
    const float* __restrict__ g, const float* __restrict__ bsh,
    float* __restrict__ xout)
{
    const int t = threadIdx.x;
    const int w = t >> 6, lane = t & 63;
    const size_t row = (size_t)blockIdx.x * 4 + w;
    const float4 xv = *(const float4*)(xin + row * 256 + lane * 4);
    const float4 yv = *(const float4*)(y + row * 256 + lane * 4);
    float4 sv;
    sv.x = xv.x + yv.x; sv.y = xv.y + yv.y; sv.z = xv.z + yv.z; sv.w = xv.w + yv.w;
    float sum = sv.x + sv.y + sv.z + sv.w;
    float sq  = sv.x * sv.x + sv.y * sv.y + sv.z * sv.z + sv.w * sv.w;
#pragma unroll
    for (int off = 1; off < 64; off <<= 1) {
        sum += __shfl_xor(sum, off, 64);
        sq  += __shfl_xor(sq, off, 64);
    }
    const float mu = sum * (1.f / 256.f);
    const float var = sq * (1.f / 256.f) - mu * mu;
    const float rs = rsqrtf(var + 1e-5f);
    const float4 gv = *(const float4*)(g + lane * 4);
    const float4 bv = *(const float4*)(bsh + lane * 4);
    float4 o;
    o.x = (sv.x - mu) * rs * gv.x + bv.x;
    o.y = (sv.y - mu) * rs * gv.y + bv.y;
    o.z = (sv.z - mu) * rs * gv.z + bv.z;
    o.w = (sv.w - mu) * rs * gv.w + bv.w;
    *(float4*)(xout + row * 256 + lane * 4) = o;
}

// ---------------------------------------------------------------------------
extern "C" void kernel_launch(void* const* d_in, const int* in_sizes, int n_in,
                              void* d_out, int out_size, void* d_ws, size_t ws_size,
                              hipStream_t stream)
{
    (void)in_sizes; (void)n_in; (void)out_size; (void)ws_size;
    const int*   tok   = (const int*)d_in[0];
    const int*   rel   = (const int*)d_in[1];
    const void*  mask  = d_in[2];
    const float* embed = (const float*)d_in[3];
    const float* W_in  = (const float*)d_in[4];
    const float* b_in  = (const float*)d_in[5];
    const float* Wq    = (const float*)d_in[6];
    const float* Wk    = (const float*)d_in[7];
    const float* Wv    = (const float*)d_in[8];
    const float* Wo    = (const float*)d_in[9];
    const float* ln1g  = (const float*)d_in[10];
    const float* ln1b  = (const float*)d_in[11];
    const float* ln2g  = (const float*)d_in[12];
    const float* ln2b  = (const float*)d_in[13];
    const float* W1    = (const float*)d_in[14];
    const float* b1    = (const float*)d_in[15];
    const float* W2    = (const float*)d_in[16];
    const float* b2    = (const float*)d_in[17];
    const float* relk  = (const float*)d_in[18];
    const float* relv  = (const float*)d_in[19];
    const float* Wout  = (const float*)d_in[20];
    const float* bout  = (const float*)d_in[21];
    float* out = (float*)d_out;

    float* ws  = (float*)d_ws;
    float* x   = ws;                       // 1M floats
    float* z   = ws + (1u << 20);          // 1M
    float* zo  = ws + 2u * (1u << 20);     // 1M
    float* qkv = ws + 3u * (1u << 20);     // 3M
    float* hb  = ws + 6u * (1u << 20);     // 4M
    int*   flag = (int*)(ws + 10u * (1u << 20));

    detect_mask_kernel<<<1, 256, 0, stream>>>((const unsigned char*)mask, flag);
    embed_proj_kernel<<<512, 256, 0, stream>>>(tok, embed, W_in, b_in, x);

    for (int l = 0; l < 4; ++l) {
        const float* wq = Wq + (size_t)l * 65536;
        const float* wk = Wk + (size_t)l * 65536;
        const float* wv = Wv + (size_t)l * 65536;
        const float* wo = Wo + (size_t)l * 65536;
        const float* w1 = W1 + (size_t)l * 262144;
        const float* w2 = W2 + (size_t)l * 262144;

        // fused QKV: [4096,256] @ 3x[256,256] -> qkv [4096,768]
        gemm_mfma<<<dim3(12, 64), 256, 0, stream>>>(x, wq, wk, wv, 256, nullptr,
                                                    qkv, NTOK, 256, 768, 0);
        attn_mfma<<<dim3(8, 8, 8), 256, 0, stream>>>(qkv, rel, mask, flag,
                                                     relk, relv, z);
        gemm_mfma<<<dim3(4, 64), 256, 0, stream>>>(z, wo, wo, wo, 256, nullptr,
                                                   zo, NTOK, 256, 256, 0);
        ln_kernel<<<1024, 256, 0, stream>>>(x, zo, ln1g + l * 256, ln1b + l * 256, x);
        gemm_mfma<<<dim3(16, 64), 256, 0, stream>>>(x, w1, w1, w1, 1024, b1 + l * 1024,
                                                    hb, NTOK, 256, 1024, 1);
        gemm_mfma<<<dim3(4, 64), 256, 0, stream>>>(hb, w2, w2, w2, 256, b2 + l * 256,
                                                   zo, NTOK, 1024, 256, 0);
        ln_kernel<<<1024, 256, 0, stream>>>(x, zo, ln2g + l * 256, ln2b + l * 256, x);
    }
    gemm_mfma<<<dim3(4, 64), 256, 0, stream>>>(x, Wout, Wout, Wout, 256, bout,
                                               out, NTOK, 256, 256, 0);
}

// Round 4
// 755.248 us; speedup vs baseline: 2.3230x; 1.0444x over previous
//
#include <hip/hip_runtime.h>
#include <hip/hip_bf16.h>

#define NTOK 4096   // B*N
#define NN   512

typedef __attribute__((ext_vector_type(8))) short bf16x8;
typedef __attribute__((ext_vector_type(4))) short bf16x4;
typedef __attribute__((ext_vector_type(4))) float f32x4;

__device__ __forceinline__ float bf16_to_f(unsigned short u) {
    unsigned int x = ((unsigned int)u) << 16;
    return __builtin_bit_cast(float, x);
}
__device__ __forceinline__ unsigned short f_to_bf16(float f) {
    unsigned int b = __builtin_bit_cast(unsigned int, f);
    return (unsigned short)((b + 0x7fff + ((b >> 16) & 1)) >> 16);
}
__device__ __forceinline__ bf16x8 pack8(float4 a, float4 b) {
    bf16x8 v;
    v[0]=(short)f_to_bf16(a.x); v[1]=(short)f_to_bf16(a.y);
    v[2]=(short)f_to_bf16(a.z); v[3]=(short)f_to_bf16(a.w);
    v[4]=(short)f_to_bf16(b.x); v[5]=(short)f_to_bf16(b.y);
    v[6]=(short)f_to_bf16(b.z); v[7]=(short)f_to_bf16(b.w);
    return v;
}

// ---------------------------------------------------------------------------
// K0: detect whether relations_mask is 1-byte bool or 4-byte int.
__global__ void detect_mask_kernel(const unsigned char* __restrict__ m, int* __restrict__ flag) {
    __shared__ int f;
    if (threadIdx.x == 0) f = 0;
    __syncthreads();
    int any = 0;
    for (int i = threadIdx.x; i < 4096; i += 256) {
        if ((i & 3) != 0 && m[i] != 0) any = 1;
    }
    if (any) atomicOr(&f, 1);
    __syncthreads();
    if (threadIdx.x == 0) *flag = f;   // 1 => byte mask, 0 => int32 mask
}

// ---------------------------------------------------------------------------
// K0b: rel16[i] = mask[i] ? relations[i] : -1   (int16). 2 elems/thread.
__global__ __launch_bounds__(256) void prep_rel16(
    const int* __restrict__ rel, const void* __restrict__ mask,
    const int* __restrict__ flag, short* __restrict__ rel16)
{
    const bool mbyte = (*flag != 0);
    const unsigned char* m8 = (const unsigned char*)mask;
    const int* m32 = (const int*)mask;
    const int i = (blockIdx.x * 256 + threadIdx.x) * 2;   // grid covers exactly B*N*N
    int2 rv = *(const int2*)(rel + i);
    int ok0, ok1;
    if (mbyte) { ok0 = m8[i]; ok1 = m8[i + 1]; }
    else       { ok0 = (m32[i] != 0); ok1 = (m32[i + 1] != 0); }
    short2 o;
    o.x = ok0 ? (short)rv.x : (short)-1;
    o.y = ok1 ? (short)rv.y : (short)-1;
    *(short2*)(rel16 + i) = o;
}

// ---------------------------------------------------------------------------
// K1: x[row,d] = relu(sum_e embed[tok[row]][e] * W_in[e][d] + b_in[d])
__global__ __launch_bounds__(256) void embed_proj_kernel(
    const int* __restrict__ tok, const float* __restrict__ embed,
    const float* __restrict__ W_in, const float* __restrict__ b_in,
    float* __restrict__ x)
{
    __shared__ float emb[8][304];
    __shared__ int tloc[8];
    const int t = threadIdx.x;
    const int r0 = blockIdx.x * 8;
    if (t < 8) tloc[t] = tok[r0 + t];
    __syncthreads();
    for (int i = t; i < 8 * 300; i += 256) {
        int r = i / 300, e = i - r * 300;
        emb[r][e] = embed[(size_t)tloc[r] * 300 + e];
    }
    __syncthreads();
    float acc[8] = {0.f,0.f,0.f,0.f,0.f,0.f,0.f,0.f};
    const int d = t;
    for (int e = 0; e < 300; ++e) {
        float w = W_in[e * 256 + d];
#pragma unroll
        for (int r = 0; r < 8; ++r) acc[r] += emb[r][e] * w;
    }
    const float bb = b_in[d];
#pragma unroll
    for (int r = 0; r < 8; ++r) {
        float o = acc[r] + bb;
        o = o > 0.f ? o : 0.f;
        x[(size_t)(r0 + r) * 256 + d] = o;
    }
}

// ---------------------------------------------------------------------------
// K2: MFMA bf16 GEMM  C[M,Nc] = act(A[M,K] @ W + bias), fp32 in/out.
__global__ __launch_bounds__(256) void gemm_mfma(
    const float* __restrict__ A,
    const float* __restrict__ W0, const float* __restrict__ W1p, const float* __restrict__ W2p,
    int ncPerW, const float* __restrict__ bias,
    float* __restrict__ C, int M, int K, int Nc, int relu)
{
    __shared__ unsigned short As[64][40];
    __shared__ unsigned short Bs[64][40];

    const int t = threadIdx.x;
    const int lane = t & 63, w = t >> 6;
    const int g = lane >> 4, li = lane & 15;
    const int r0 = blockIdx.y * 64, c0 = blockIdx.x * 64;

    const float* Wp = W0; int cW = c0;
    if (c0 >= 2 * ncPerW)      { Wp = W2p; cW = c0 - 2 * ncPerW; }
    else if (c0 >= ncPerW)     { Wp = W1p; cW = c0 - ncPerW; }

    f32x4 acc[4];
#pragma unroll
    for (int i = 0; i < 4; ++i) acc[i] = (f32x4){0.f, 0.f, 0.f, 0.f};

    const int arow = t >> 2, ad8 = (t & 3) * 8;
    const int bnn = t & 63, bk8 = (t >> 6) * 8;

    for (int k0 = 0; k0 < K; k0 += 32) {
        __syncthreads();
        {
            const float* ap = A + (size_t)(r0 + arow) * K + k0 + ad8;
            float4 a0 = *(const float4*)ap;
            float4 a1 = *(const float4*)(ap + 4);
            *(bf16x8*)&As[arow][ad8] = pack8(a0, a1);
        }
        {
            bf16x8 v;
#pragma unroll
            for (int j = 0; j < 8; ++j) {
                float xv = Wp[(size_t)(k0 + bk8 + j) * ncPerW + cW + bnn];
                v[j] = (short)f_to_bf16(xv);
            }
            *(bf16x8*)&Bs[bnn][bk8] = v;
        }
        __syncthreads();
        bf16x8 af = *(const bf16x8*)&As[16 * w + li][g * 8];
#pragma unroll
        for (int sub = 0; sub < 4; ++sub) {
            bf16x8 bfr = *(const bf16x8*)&Bs[16 * sub + li][g * 8];
            acc[sub] = __builtin_amdgcn_mfma_f32_16x16x32_bf16(af, bfr, acc[sub], 0, 0, 0);
        }
    }
#pragma unroll
    for (int sub = 0; sub < 4; ++sub) {
        int col = c0 + sub * 16 + li;
        float bv = bias ? bias[col] : 0.f;
#pragma unroll
        for (int r = 0; r < 4; ++r) {
            int row = r0 + 16 * w + g * 4 + r;
            float o = acc[sub][r] + bv;
            if (relu) o = fmaxf(o, 0.f);
            C[(size_t)row * Nc + col] = o;
        }
    }
}

// ---------------------------------------------------------------------------
// K3: relation-aware attention via MFMA. All inner-loop accesses are LDS-only
// (rel16 tile staged coalesced). LDS = 53248 B -> 3 blocks/CU.
__global__ __launch_bounds__(256) void attn_mfma(
    const float* __restrict__ qkv,       // [BN, 768] (q|k|v)
    const short* __restrict__ rel16,     // [B,N,N] mask-folded relations
    const float* __restrict__ relk_g,    // [100,32]
    const float* __restrict__ relv_g,
    float* __restrict__ zout)            // [BN, 256]
{
    const int b = blockIdx.z, h = blockIdx.y, n0 = blockIdx.x * 64;
    const int t = threadIdx.x;
    const int lane = t & 63, w = t >> 6;
    const int g = lane >> 4, li = lane & 15;

    __shared__ float wrel[64][100];            // 25600 B, persistent
    __shared__ unsigned short qrk[64][100];    // 12800 B, persistent
    __shared__ union {
        unsigned short relk_s[100][40];        // phase B (8000 B)
        unsigned short relvT[32][136];         // phase W (8704 B)
        struct {
            unsigned short k_t[32][40];        // [m][d]
            unsigned short v_t[32][40];        // [d][m]
            short rel_t[64][36];               // [q][m]
            unsigned short p_s[4][16][40];     // per-wave P [q][m]
        } mn;                                  // main loop (14848 B)
    } u;                                       // total 53248 B

    // ---- Phase A: zero wrel, stage relk (bf16), load Q frag
    for (int i = t; i < 6400; i += 256) ((float*)wrel)[i] = 0.f;
    for (int i = t; i < 400; i += 256) {
        int rr = i >> 2, d8 = (i & 3) * 8;
        const float* sp = relk_g + rr * 32 + d8;
        *(bf16x8*)&u.relk_s[rr][d8] = pack8(*(const float4*)sp, *(const float4*)(sp + 4));
    }
    const float scale = 0.17677669529663687f;
    bf16x8 qf;
    {
        const float* qp = qkv + (size_t)(b * NN + n0 + 16 * w + li) * 768 + h * 32 + g * 8;
        float4 q0 = *(const float4*)qp, q1 = *(const float4*)(qp + 4);
        q0.x *= scale; q0.y *= scale; q0.z *= scale; q0.w *= scale;
        q1.x *= scale; q1.y *= scale; q1.z *= scale; q1.w *= scale;
        qf = pack8(q0, q1);
    }
    __syncthreads();

    // ---- Phase B: qrk = Q @ relk^T  (cols = rel, 7 chunks of 16)
#pragma unroll
    for (int rc = 0; rc < 7; ++rc) {
        bf16x8 bb = *(const bf16x8*)&u.relk_s[rc * 16 + li][g * 8];
        f32x4 s = __builtin_amdgcn_mfma_f32_16x16x32_bf16(qf, bb, (f32x4){0.f,0.f,0.f,0.f}, 0, 0, 0);
        int col = rc * 16 + li;
        if (col < 100) {
#pragma unroll
            for (int r = 0; r < 4; ++r)
                qrk[16 * w + g * 4 + r][col] = f_to_bf16(s[r]);
        }
    }
    __syncthreads();

    float smacc[4] = {0.f, 0.f, 0.f, 0.f};
    f32x4 zf[2];
    zf[0] = (f32x4){0.f,0.f,0.f,0.f};
    zf[1] = (f32x4){0.f,0.f,0.f,0.f};
    const size_t relbase = ((size_t)b * NN + n0) * NN;   // rel16[b][n0+..][..]

    // ---- Main loop over 16 m-tiles of 32
    for (int mt = 0; mt < 16; ++mt) {
        const int m0 = mt * 32;
        __syncthreads();
        {   // stage K tile [32 m][32 d]
            int row = t >> 3, d4 = (t & 7) * 4;
            const float* kp = qkv + (size_t)(b * NN + m0 + row) * 768 + 256 + h * 32 + d4;
            float4 kv4 = *(const float4*)kp;
            bf16x4 kv;
            kv[0]=(short)f_to_bf16(kv4.x); kv[1]=(short)f_to_bf16(kv4.y);
            kv[2]=(short)f_to_bf16(kv4.z); kv[3]=(short)f_to_bf16(kv4.w);
            *(bf16x4*)&u.mn.k_t[row][d4] = kv;
        }
        {   // stage V tile transposed [32 d][32 m]
            int m = t & 31, dg = t >> 5;
            const float* vp = qkv + (size_t)(b * NN + m0 + m) * 768 + 512 + h * 32 + dg * 4;
            float4 vv = *(const float4*)vp;
            u.mn.v_t[dg * 4 + 0][m] = f_to_bf16(vv.x);
            u.mn.v_t[dg * 4 + 1][m] = f_to_bf16(vv.y);
            u.mn.v_t[dg * 4 + 2][m] = f_to_bf16(vv.z);
            u.mn.v_t[dg * 4 + 3][m] = f_to_bf16(vv.w);
        }
        {   // stage rel16 tile [64 q][32 m] via int2 (4 shorts), 2 per thread
#pragma unroll
            for (int ii = 0; ii < 2; ++ii) {
                int i = t * 2 + ii;            // 0..511
                int rr = i >> 3, m4 = (i & 7) * 4;
                int2 rv = *(const int2*)(rel16 + relbase + (size_t)rr * NN + m0 + m4);
                *(int2*)&u.mn.rel_t[rr][m4] = rv;
            }
        }
        __syncthreads();
        // QK^T + score post-processing (2 chunks of 16 m) — LDS only
#pragma unroll
        for (int c = 0; c < 2; ++c) {
            bf16x8 kf = *(const bf16x8*)&u.mn.k_t[c * 16 + li][g * 8];
            f32x4 s = __builtin_amdgcn_mfma_f32_16x16x32_bf16(qf, kf, (f32x4){0.f,0.f,0.f,0.f}, 0, 0, 0);
            const int mm = c * 16 + li;
#pragma unroll
            for (int r = 0; r < 4; ++r) {
                const int ql = 16 * w + g * 4 + r;
                const int rl = u.mn.rel_t[ql][mm];
                float p = 0.f;
                if (rl >= 0) {
                    float sc = s[r] + bf16_to_f(qrk[ql][rl]);
                    p = __expf(fminf(sc, 50.f));
                    atomicAdd(&wrel[ql][rl], p);
                }
                smacc[r] += p;
                u.mn.p_s[w][g * 4 + r][mm] = f_to_bf16(p);
            }
        }
        asm volatile("s_waitcnt lgkmcnt(0)" ::: "memory");
        __builtin_amdgcn_sched_barrier(0);
        // PV: z += P @ V
        bf16x8 pa = *(const bf16x8*)&u.mn.p_s[w][li][g * 8];
#pragma unroll
        for (int dc = 0; dc < 2; ++dc) {
            bf16x8 vb = *(const bf16x8*)&u.mn.v_t[dc * 16 + li][g * 8];
            zf[dc] = __builtin_amdgcn_mfma_f32_16x16x32_bf16(pa, vb, zf[dc], 0, 0, 0);
        }
    }
    __syncthreads();   // wrel atomics complete; main-loop LDS free

    // ---- stage relv TRANSPOSED: relvT[d][rel]; zero rel 100..135
    for (int i = t; i < 32 * 36; i += 256) {
        int d = i / 36, c = 100 + (i - (i / 36) * 36);
        u.relvT[d][c] = 0;
    }
    for (int i = t; i < 400; i += 256) {
        int rr = i >> 2, d8 = (i & 3) * 8;
        const float* sp = relv_g + rr * 32 + d8;
        float4 s0 = *(const float4*)sp, s1 = *(const float4*)(sp + 4);
        u.relvT[d8 + 0][rr] = f_to_bf16(s0.x);
        u.relvT[d8 + 1][rr] = f_to_bf16(s0.y);
        u.relvT[d8 + 2][rr] = f_to_bf16(s0.z);
        u.relvT[d8 + 3][rr] = f_to_bf16(s0.w);
        u.relvT[d8 + 4][rr] = f_to_bf16(s1.x);
        u.relvT[d8 + 5][rr] = f_to_bf16(s1.y);
        u.relvT[d8 + 6][rr] = f_to_bf16(s1.z);
        u.relvT[d8 + 7][rr] = f_to_bf16(s1.w);
    }
    __syncthreads();

    // ---- Phase W: z += W @ relv  (K = rel, 4 chunks of 32, zero-guarded >=100)
#pragma unroll
    for (int kc = 0; kc < 4; ++kc) {
        const int kbase = kc * 32 + g * 8;
        const float* wp = &wrel[16 * w + li][0];
        bf16x8 af;
#pragma unroll
        for (int j = 0; j < 8; ++j) {
            int idx = kbase + j;
            float val = (idx < 100) ? wp[idx] : 0.f;
            af[j] = (short)f_to_bf16(val);
        }
#pragma unroll
        for (int dc = 0; dc < 2; ++dc) {
            bf16x8 vb = *(const bf16x8*)&u.relvT[dc * 16 + li][kbase];
            zf[dc] = __builtin_amdgcn_mfma_f32_16x16x32_bf16(af, vb, zf[dc], 0, 0, 0);
        }
    }

    // ---- row sums (reduce across the 16 m-column lanes) and store
#pragma unroll
    for (int r = 0; r < 4; ++r) {
        smacc[r] += __shfl_xor(smacc[r], 1, 64);
        smacc[r] += __shfl_xor(smacc[r], 2, 64);
        smacc[r] += __shfl_xor(smacc[r], 4, 64);
        smacc[r] += __shfl_xor(smacc[r], 8, 64);
    }
#pragma unroll
    for (int r = 0; r < 4; ++r) {
        float inv = 1.f / smacc[r];
        size_t ob = ((size_t)(b * NN + n0 + 16 * w + g * 4 + r)) * 256 + h * 32;
#pragma unroll
        for (int dc = 0; dc < 2; ++dc)
            zout[ob + dc * 16 + li] = zf[dc][r] * inv;
    }
}

// ---------------------------------------------------------------------------
// K4: x = LayerNorm(xin + y) * g + b
__global__ __launch_bounds__(256) void ln_kernel(
    const float* __restrict__ xin, const float* __restrict__ y,
    const float* __restrict__ g, const float* __restrict__ bsh,
    float* __restrict__ xout)
{
    const int t = threadIdx.x;
    const int w = t >> 6, lane = t & 63;
    const size_t row = (size_t)blockIdx.x * 4 + w;
    const float4 xv = *(const float4*)(xin + row * 256 + lane * 4);
    const float4 yv = *(const float4*)(y + row * 256 + lane * 4);
    float4 sv;
    sv.x = xv.x + yv.x; sv.y = xv.y + yv.y; sv.z = xv.z + yv.z; sv.w = xv.w + yv.w;
    float sum = sv.x + sv.y + sv.z + sv.w;
    float sq  = sv.x * sv.x + sv.y * sv.y + sv.z * sv.z + sv.w * sv.w;
#pragma unroll
    for (int off = 1; off < 64; off <<= 1) {
        sum += __shfl_xor(sum, off, 64);
        sq  += __shfl_xor(sq, off, 64);
    }
    const float mu = sum * (1.f / 256.f);
    const float var = sq * (1.f / 256.f) - mu * mu;
    const float rs = rsqrtf(var + 1e-5f);
    const float4 gv = *(const float4*)(g + lane * 4);
    const float4 bv = *(const float4*)(bsh + lane * 4);
    float4 o;
    o.x = (sv.x - mu) * rs * gv.x + bv.x;
    o.y = (sv.y - mu) * rs * gv.y + bv.y;
    o.z = (sv.z - mu) * rs * gv.z + bv.z;
    o.w = (sv.w - mu) * rs * gv.w + bv.w;
    *(float4*)(xout + row * 256 + lane * 4) = o;
}

// ---------------------------------------------------------------------------
extern "C" void kernel_launch(void* const* d_in, const int* in_sizes, int n_in,
                              void* d_out, int out_size, void* d_ws, size_t ws_size,
                              hipStream_t stream)
{
    (void)in_sizes; (void)n_in; (void)out_size;
    const int*   tok   = (const int*)d_in[0];
    const int*   rel   = (const int*)d_in[1];
    const void*  mask  = d_in[2];
    const float* embed = (const float*)d_in[3];
    const float* W_in  = (const float*)d_in[4];
    const float* b_in  = (const float*)d_in[5];
    const float* Wq    = (const float*)d_in[6];
    const float* Wk    = (const float*)d_in[7];
    const float* Wv    = (const float*)d_in[8];
    const float* Wo    = (const float*)d_in[9];
    const float* ln1g  = (const float*)d_in[10];
    const float* ln1b  = (const float*)d_in[11];
    const float* ln2g  = (const float*)d_in[12];
    const float* ln2b  = (const float*)d_in[13];
    const float* W1    = (const float*)d_in[14];
    const float* b1    = (const float*)d_in[15];
    const float* W2    = (const float*)d_in[16];
    const float* b2    = (const float*)d_in[17];
    const float* relk  = (const float*)d_in[18];
    const float* relv  = (const float*)d_in[19];
    const float* Wout  = (const float*)d_in[20];
    const float* bout  = (const float*)d_in[21];
    float* out = (float*)d_out;

    float* ws  = (float*)d_ws;
    float* x   = ws;                       // 1M floats
    float* z   = ws + (1u << 20);          // 1M
    float* zo  = ws + 2u * (1u << 20);     // 1M
    float* qkv = ws + 3u * (1u << 20);     // 3M
    float* hb  = ws + 6u * (1u << 20);     // 4M  (FFN hidden; free during attn)

    // rel16: dedicated region if ws is roomy, else reuse hb (re-prepped per layer).
    const bool roomy = ws_size >= ((size_t)48 << 20);
    short* rel16 = roomy ? (short*)(ws + 10u * (1u << 20)) : (short*)hb;
    int*   flag  = (int*)(ws + (roomy ? 11u : 10u) * (1u << 20));

    detect_mask_kernel<<<1, 256, 0, stream>>>((const unsigned char*)mask, flag);
    if (roomy)
        prep_rel16<<<4096, 256, 0, stream>>>(rel, mask, flag, rel16);
    embed_proj_kernel<<<512, 256, 0, stream>>>(tok, embed, W_in, b_in, x);

    for (int l = 0; l < 4; ++l) {
        const float* wq = Wq + (size_t)l * 65536;
        const float* wk = Wk + (size_t)l * 65536;
        const float* wv = Wv + (size_t)l * 65536;
        const float* wo = Wo + (size_t)l * 65536;
        const float* w1 = W1 + (size_t)l * 262144;
        const float* w2 = W2 + (size_t)l * 262144;

        if (!roomy)
            prep_rel16<<<4096, 256, 0, stream>>>(rel, mask, flag, rel16);

        // fused QKV: [4096,256] @ 3x[256,256] -> qkv [4096,768]
        gemm_mfma<<<dim3(12, 64), 256, 0, stream>>>(x, wq, wk, wv, 256, nullptr,
                                                    qkv, NTOK, 256, 768, 0);
        attn_mfma<<<dim3(8, 8, 8), 256, 0, stream>>>(qkv, rel16, relk, relv, z);
        gemm_mfma<<<dim3(4, 64), 256, 0, stream>>>(z, wo, wo, wo, 256, nullptr,
                                                   zo, NTOK, 256, 256, 0);
        ln_kernel<<<1024, 256, 0, stream>>>(x, zo, ln1g + l * 256, ln1b + l * 256, x);
        gemm_mfma<<<dim3(16, 64), 256, 0, stream>>>(x, w1, w1, w1, 1024, b1 + l * 1024,
                                                    hb, NTOK, 256, 1024, 1);
        gemm_mfma<<<dim3(4, 64), 256, 0, stream>>>(hb, w2, w2, w2, 256, b2 + l * 256,
                                                   zo, NTOK, 1024, 256, 0);
        ln_kernel<<<1024, 256, 0, stream>>>(x, zo, ln2g + l * 256, ln2b + l * 256, x);
    }
    gemm_mfma<<<dim3(4, 64), 256, 0, stream>>>(x, Wout, Wout, Wout, 256, bout,
                                               out, NTOK, 256, 256, 0);
}

// Round 5
// 638.004 us; speedup vs baseline: 2.7499x; 1.1838x over previous
//
#include <hip/hip_runtime.h>
#include <hip/hip_bf16.h>

#define NTOK 4096   // B*N
#define NN   512

typedef __attribute__((ext_vector_type(8))) short bf16x8;
typedef __attribute__((ext_vector_type(4))) short bf16x4;
typedef __attribute__((ext_vector_type(4))) float f32x4;

__device__ __forceinline__ float bf16_to_f(unsigned short u) {
    unsigned int x = ((unsigned int)u) << 16;
    return __builtin_bit_cast(float, x);
}
__device__ __forceinline__ unsigned short f_to_bf16(float f) {
    unsigned int b = __builtin_bit_cast(unsigned int, f);
    return (unsigned short)((b + 0x7fff + ((b >> 16) & 1)) >> 16);
}
__device__ __forceinline__ bf16x8 pack8(float4 a, float4 b) {
    bf16x8 v;
    v[0]=(short)f_to_bf16(a.x); v[1]=(short)f_to_bf16(a.y);
    v[2]=(short)f_to_bf16(a.z); v[3]=(short)f_to_bf16(a.w);
    v[4]=(short)f_to_bf16(b.x); v[5]=(short)f_to_bf16(b.y);
    v[6]=(short)f_to_bf16(b.z); v[7]=(short)f_to_bf16(b.w);
    return v;
}

// ---------------------------------------------------------------------------
// K0: detect whether relations_mask is 1-byte bool or 4-byte int.
__global__ void detect_mask_kernel(const unsigned char* __restrict__ m, int* __restrict__ flag) {
    __shared__ int f;
    if (threadIdx.x == 0) f = 0;
    __syncthreads();
    int any = 0;
    for (int i = threadIdx.x; i < 4096; i += 256) {
        if ((i & 3) != 0 && m[i] != 0) any = 1;
    }
    if (any) atomicOr(&f, 1);
    __syncthreads();
    if (threadIdx.x == 0) *flag = f;   // 1 => byte mask, 0 => int32 mask
}

// ---------------------------------------------------------------------------
// K0b: rel16[i] = mask[i] ? relations[i] : -1   (int16). 2 elems/thread.
__global__ __launch_bounds__(256) void prep_rel16(
    const int* __restrict__ rel, const void* __restrict__ mask,
    const int* __restrict__ flag, short* __restrict__ rel16)
{
    const bool mbyte = (*flag != 0);
    const unsigned char* m8 = (const unsigned char*)mask;
    const int* m32 = (const int*)mask;
    const int i = (blockIdx.x * 256 + threadIdx.x) * 2;
    int2 rv = *(const int2*)(rel + i);
    int ok0, ok1;
    if (mbyte) { ok0 = m8[i]; ok1 = m8[i + 1]; }
    else       { ok0 = (m32[i] != 0); ok1 = (m32[i + 1] != 0); }
    short2 o;
    o.x = ok0 ? (short)rv.x : (short)-1;
    o.y = ok1 ? (short)rv.y : (short)-1;
    *(short2*)(rel16 + i) = o;
}

// ---------------------------------------------------------------------------
// K1: x[row,d] = relu(sum_e embed[tok[row]][e] * W_in[e][d] + b_in[d])
__global__ __launch_bounds__(256) void embed_proj_kernel(
    const int* __restrict__ tok, const float* __restrict__ embed,
    const float* __restrict__ W_in, const float* __restrict__ b_in,
    float* __restrict__ x)
{
    __shared__ float emb[8][304];
    __shared__ int tloc[8];
    const int t = threadIdx.x;
    const int r0 = blockIdx.x * 8;
    if (t < 8) tloc[t] = tok[r0 + t];
    __syncthreads();
    for (int i = t; i < 8 * 300; i += 256) {
        int r = i / 300, e = i - r * 300;
        emb[r][e] = embed[(size_t)tloc[r] * 300 + e];
    }
    __syncthreads();
    float acc[8] = {0.f,0.f,0.f,0.f,0.f,0.f,0.f,0.f};
    const int d = t;
    for (int e = 0; e < 300; ++e) {
        float w = W_in[e * 256 + d];
#pragma unroll
        for (int r = 0; r < 8; ++r) acc[r] += emb[r][e] * w;
    }
    const float bb = b_in[d];
#pragma unroll
    for (int r = 0; r < 8; ++r) {
        float o = acc[r] + bb;
        o = o > 0.f ? o : 0.f;
        x[(size_t)(r0 + r) * 256 + d] = o;
    }
}

// ---------------------------------------------------------------------------
// K2: MFMA bf16 GEMM, double-buffered LDS + register prefetch (T14).
// One barrier per K-step; loads for step k+1 in flight during compute of k.
__global__ __launch_bounds__(256) void gemm_mfma(
    const float* __restrict__ A,
    const float* __restrict__ W0, const float* __restrict__ W1p, const float* __restrict__ W2p,
    int ncPerW, const float* __restrict__ bias,
    float* __restrict__ C, int M, int K, int Nc, int relu)
{
    __shared__ unsigned short As[2][64][40];
    __shared__ unsigned short Bs[2][64][40];

    const int t = threadIdx.x;
    const int lane = t & 63, w = t >> 6;
    const int g = lane >> 4, li = lane & 15;
    const int r0 = blockIdx.y * 64, c0 = blockIdx.x * 64;

    const float* Wp = W0; int cW = c0;
    if (c0 >= 2 * ncPerW)      { Wp = W2p; cW = c0 - 2 * ncPerW; }
    else if (c0 >= ncPerW)     { Wp = W1p; cW = c0 - ncPerW; }

    f32x4 acc[4];
#pragma unroll
    for (int i = 0; i < 4; ++i) acc[i] = (f32x4){0.f, 0.f, 0.f, 0.f};

    const int arow = t >> 2, ad8 = (t & 3) * 8;
    const int bnn = t & 63, bk8 = (t >> 6) * 8;

    // prologue loads (k0 = 0)
    const float* ap0 = A + (size_t)(r0 + arow) * K + ad8;
    float4 a0 = *(const float4*)ap0;
    float4 a1 = *(const float4*)(ap0 + 4);
    float wv[8];
#pragma unroll
    for (int j = 0; j < 8; ++j)
        wv[j] = Wp[(size_t)(bk8 + j) * ncPerW + cW + bnn];

    const int nk = K >> 5;
    for (int ki = 0; ki < nk; ++ki) {
        const int cur = ki & 1;
        *(bf16x8*)&As[cur][arow][ad8] = pack8(a0, a1);
        {
            bf16x8 v;
#pragma unroll
            for (int j = 0; j < 8; ++j) v[j] = (short)f_to_bf16(wv[j]);
            *(bf16x8*)&Bs[cur][bnn][bk8] = v;
        }
        if (ki + 1 < nk) {   // prefetch next K-step
            const int k0 = (ki + 1) * 32;
            const float* ap = A + (size_t)(r0 + arow) * K + k0 + ad8;
            a0 = *(const float4*)ap;
            a1 = *(const float4*)(ap + 4);
#pragma unroll
            for (int j = 0; j < 8; ++j)
                wv[j] = Wp[(size_t)(k0 + bk8 + j) * ncPerW + cW + bnn];
        }
        __syncthreads();
        bf16x8 af = *(const bf16x8*)&As[cur][16 * w + li][g * 8];
#pragma unroll
        for (int sub = 0; sub < 4; ++sub) {
            bf16x8 bfr = *(const bf16x8*)&Bs[cur][16 * sub + li][g * 8];
            acc[sub] = __builtin_amdgcn_mfma_f32_16x16x32_bf16(af, bfr, acc[sub], 0, 0, 0);
        }
    }
#pragma unroll
    for (int sub = 0; sub < 4; ++sub) {
        int col = c0 + sub * 16 + li;
        float bv = bias ? bias[col] : 0.f;
#pragma unroll
        for (int r = 0; r < 4; ++r) {
            int row = r0 + 16 * w + g * 4 + r;
            float o = acc[sub][r] + bv;
            if (relu) o = fmaxf(o, 0.f);
            C[(size_t)row * Nc + col] = o;
        }
    }
}

// ---------------------------------------------------------------------------
// K3: relation-aware attention via MFMA.
//  - rel16 loads straight to regs (each element consumed by exactly one lane),
//    prefetched one m-tile ahead; no LDS round-trip.
//  - K/V: register prefetch + double-buffered LDS, ONE barrier per tile.
//  - 1D grid with XCD-grouped decode: the 8 head-blocks sharing a rel16 slice
//    land on the same XCD (p%8), so the slice is fetched once per XCD.
__global__ __launch_bounds__(256) void attn_mfma(
    const float* __restrict__ qkv,       // [BN, 768] (q|k|v)
    const short* __restrict__ rel16,     // [B,N,N] mask-folded relations
    const float* __restrict__ relk_g,    // [100,32]
    const float* __restrict__ relv_g,
    float* __restrict__ zout)            // [BN, 256]
{
    const int p = blockIdx.x;            // 0..511
    const int cx = p & 7, kk = p >> 3;
    const int bc = cx * 8 + (kk >> 3);   // slice id: (b, chunk)
    const int h  = kk & 7;
    const int b  = bc >> 3;
    const int n0 = (bc & 7) * 64;

    const int t = threadIdx.x;
    const int lane = t & 63, w = t >> 6;
    const int g = lane >> 4, li = lane & 15;
    const int qrow = 16 * w + g * 4;     // +r

    __shared__ float wrel[64][100];            // 25600 B, persistent
    __shared__ unsigned short qrk[64][100];    // 12800 B, persistent
    __shared__ union {
        unsigned short relk_s[100][40];        // phase B (8000 B)
        unsigned short relvT[32][136];         // phase W (8704 B)
        struct {
            unsigned short k_t[2][32][40];     // [buf][m][d]   5120 B
            unsigned short v_t[2][32][40];     // [buf][d][m]   5120 B
            unsigned short p_s[4][16][40];     // per-wave P    5120 B
        } mn;                                  // 15360 B
    } u;                                       // total 53760 B -> 3 blocks/CU

    // ---- Phase A: zero wrel, stage relk (bf16), load Q frag
    for (int i = t; i < 6400; i += 256) ((float*)wrel)[i] = 0.f;
    for (int i = t; i < 400; i += 256) {
        int rr = i >> 2, d8 = (i & 3) * 8;
        const float* sp = relk_g + rr * 32 + d8;
        *(bf16x8*)&u.relk_s[rr][d8] = pack8(*(const float4*)sp, *(const float4*)(sp + 4));
    }
    const float scale = 0.17677669529663687f;
    bf16x8 qf;
    {
        const float* qp = qkv + (size_t)(b * NN + n0 + 16 * w + li) * 768 + h * 32 + g * 8;
        float4 q0 = *(const float4*)qp, q1 = *(const float4*)(qp + 4);
        q0.x *= scale; q0.y *= scale; q0.z *= scale; q0.w *= scale;
        q1.x *= scale; q1.y *= scale; q1.z *= scale; q1.w *= scale;
        qf = pack8(q0, q1);
    }
    __syncthreads();

    // ---- Phase B: qrk = Q @ relk^T  (cols = rel, 7 chunks of 16)
#pragma unroll
    for (int rc = 0; rc < 7; ++rc) {
        bf16x8 bb = *(const bf16x8*)&u.relk_s[rc * 16 + li][g * 8];
        f32x4 s = __builtin_amdgcn_mfma_f32_16x16x32_bf16(qf, bb, (f32x4){0.f,0.f,0.f,0.f}, 0, 0, 0);
        int col = rc * 16 + li;
        if (col < 100) {
#pragma unroll
            for (int r = 0; r < 4; ++r)
                qrk[qrow + r][col] = f_to_bf16(s[r]);
        }
    }

    float smacc[4] = {0.f, 0.f, 0.f, 0.f};
    f32x4 zf[2];
    zf[0] = (f32x4){0.f,0.f,0.f,0.f};
    zf[1] = (f32x4){0.f,0.f,0.f,0.f};

    // per-lane rel row pointers (q-rows this lane owns)
    const short* relrow[4];
#pragma unroll
    for (int r = 0; r < 4; ++r)
        relrow[r] = rel16 + ((size_t)b * NN + n0 + qrow + r) * NN;

    // staging index maps
    const int krow = t >> 3, kd4 = (t & 7) * 4;       // K: [m][d] float4
    const int vm = t & 31, vdg = t >> 5;              // V: [d][m] transpose
    const size_t kbase0 = (size_t)(b * NN) * 768 + 256 + h * 32;
    const size_t vbase0 = (size_t)(b * NN) * 768 + 512 + h * 32;

    // prologue: load tile 0 K/V + rel into regs
    float4 kreg = *(const float4*)(qkv + kbase0 + (size_t)krow * 768 + kd4);
    float4 vreg = *(const float4*)(qkv + vbase0 + (size_t)vm * 768 + vdg * 4);
    short rr[8], rn[8];
#pragma unroll
    for (int idx = 0; idx < 8; ++idx)
        rr[idx] = relrow[idx & 3][(idx >> 2) * 16 + li];

    __syncthreads();   // phase B qrk writes complete; mn space free

    // ---- Main loop over 16 m-tiles of 32 (one barrier per tile)
    for (int mt = 0; mt < 16; ++mt) {
        const int cur = mt & 1;
        {   // write staged K tile [32 m][32 d]
            bf16x4 kv;
            kv[0]=(short)f_to_bf16(kreg.x); kv[1]=(short)f_to_bf16(kreg.y);
            kv[2]=(short)f_to_bf16(kreg.z); kv[3]=(short)f_to_bf16(kreg.w);
            *(bf16x4*)&u.mn.k_t[cur][krow][kd4] = kv;
        }
        {   // write staged V tile transposed [32 d][32 m]
            u.mn.v_t[cur][vdg * 4 + 0][vm] = f_to_bf16(vreg.x);
            u.mn.v_t[cur][vdg * 4 + 1][vm] = f_to_bf16(vreg.y);
            u.mn.v_t[cur][vdg * 4 + 2][vm] = f_to_bf16(vreg.z);
            u.mn.v_t[cur][vdg * 4 + 3][vm] = f_to_bf16(vreg.w);
        }
        if (mt + 1 < 16) {   // prefetch next tile (global loads in flight across barrier)
            const int m0n = (mt + 1) * 32;
            kreg = *(const float4*)(qkv + kbase0 + (size_t)(m0n + krow) * 768 + kd4);
            vreg = *(const float4*)(qkv + vbase0 + (size_t)(m0n + vm) * 768 + vdg * 4);
#pragma unroll
            for (int idx = 0; idx < 8; ++idx)
                rn[idx] = relrow[idx & 3][m0n + (idx >> 2) * 16 + li];
        }
        __syncthreads();

        // QK^T (2 chunks of 16 m)
        bf16x8 kf0 = *(const bf16x8*)&u.mn.k_t[cur][li][g * 8];
        bf16x8 kf1 = *(const bf16x8*)&u.mn.k_t[cur][16 + li][g * 8];
        f32x4 s0 = __builtin_amdgcn_mfma_f32_16x16x32_bf16(qf, kf0, (f32x4){0.f,0.f,0.f,0.f}, 0, 0, 0);
        f32x4 s1 = __builtin_amdgcn_mfma_f32_16x16x32_bf16(qf, kf1, (f32x4){0.f,0.f,0.f,0.f}, 0, 0, 0);

        float pr[8];
#pragma unroll
        for (int idx = 0; idx < 8; ++idx) {
            const int r = idx & 3;
            const int rl = rr[idx];
            const int rla = rl < 0 ? 0 : rl;
            const float qadd = bf16_to_f(qrk[qrow + r][rla]);
            const float sv = ((idx >> 2) ? s1[r] : s0[r]) + qadd;
            float pv = 0.f;
            if (rl >= 0) {
                pv = __expf(fminf(sv, 50.f));
                atomicAdd(&wrel[qrow + r][rl], pv);
            }
            smacc[r] += pv;
            pr[idx] = pv;
        }
#pragma unroll
        for (int idx = 0; idx < 8; ++idx)
            u.mn.p_s[w][g * 4 + (idx & 3)][(idx >> 2) * 16 + li] = f_to_bf16(pr[idx]);

        asm volatile("s_waitcnt lgkmcnt(0)" ::: "memory");
        __builtin_amdgcn_sched_barrier(0);

        // PV: z += P @ V
        bf16x8 pa = *(const bf16x8*)&u.mn.p_s[w][li][g * 8];
#pragma unroll
        for (int dc = 0; dc < 2; ++dc) {
            bf16x8 vb = *(const bf16x8*)&u.mn.v_t[cur][dc * 16 + li][g * 8];
            zf[dc] = __builtin_amdgcn_mfma_f32_16x16x32_bf16(pa, vb, zf[dc], 0, 0, 0);
        }
#pragma unroll
        for (int idx = 0; idx < 8; ++idx) rr[idx] = rn[idx];
    }
    __syncthreads();   // wrel atomics complete; main-loop LDS free

    // ---- stage relv TRANSPOSED: relvT[d][rel]; zero rel 100..135
    for (int i = t; i < 32 * 36; i += 256) {
        int d = i / 36, c = 100 + (i - (i / 36) * 36);
        u.relvT[d][c] = 0;
    }
    for (int i = t; i < 400; i += 256) {
        int rr2 = i >> 2, d8 = (i & 3) * 8;
        const float* sp = relv_g + rr2 * 32 + d8;
        float4 s0 = *(const float4*)sp, s1 = *(const float4*)(sp + 4);
        u.relvT[d8 + 0][rr2] = f_to_bf16(s0.x);
        u.relvT[d8 + 1][rr2] = f_to_bf16(s0.y);
        u.relvT[d8 + 2][rr2] = f_to_bf16(s0.z);
        u.relvT[d8 + 3][rr2] = f_to_bf16(s0.w);
        u.relvT[d8 + 4][rr2] = f_to_bf16(s1.x);
        u.relvT[d8 + 5][rr2] = f_to_bf16(s1.y);
        u.relvT[d8 + 6][rr2] = f_to_bf16(s1.z);
        u.relvT[d8 + 7][rr2] = f_to_bf16(s1.w);
    }
    __syncthreads();

    // ---- Phase W: z += W @ relv  (K = rel, 4 chunks of 32, zero-guarded >=100)
#pragma unroll
    for (int kc = 0; kc < 4; ++kc) {
        const int kbase = kc * 32 + g * 8;
        const float* wp = &wrel[16 * w + li][0];
        bf16x8 af;
#pragma unroll
        for (int j = 0; j < 8; ++j) {
            int idx = kbase + j;
            float val = (idx < 100) ? wp[idx] : 0.f;
            af[j] = (short)f_to_bf16(val);
        }
#pragma unroll
        for (int dc = 0; dc < 2; ++dc) {
            bf16x8 vb = *(const bf16x8*)&u.relvT[dc * 16 + li][kbase];
            zf[dc] = __builtin_amdgcn_mfma_f32_16x16x32_bf16(af, vb, zf[dc], 0, 0, 0);
        }
    }

    // ---- row sums (reduce across the 16 m-column lanes) and store
#pragma unroll
    for (int r = 0; r < 4; ++r) {
        smacc[r] += __shfl_xor(smacc[r], 1, 64);
        smacc[r] += __shfl_xor(smacc[r], 2, 64);
        smacc[r] += __shfl_xor(smacc[r], 4, 64);
        smacc[r] += __shfl_xor(smacc[r], 8, 64);
    }
#pragma unroll
    for (int r = 0; r < 4; ++r) {
        float inv = 1.f / smacc[r];
        size_t ob = ((size_t)(b * NN + n0 + qrow + r)) * 256 + h * 32;
#pragma unroll
        for (int dc = 0; dc < 2; ++dc)
            zout[ob + dc * 16 + li] = zf[dc][r] * inv;
    }
}

// ---------------------------------------------------------------------------
// K4: x = LayerNorm(xin + y) * g + b
__global__ __launch_bounds__(256) void ln_kernel(
    const float* __restrict__ xin, const float* __restrict__ y,
    const float* __restrict__ g, const float* __restrict__ bsh,
    float* __restrict__ xout)
{
    const int t = threadIdx.x;
    const int w = t >> 6, lane = t & 63;
    const size_t row = (size_t)blockIdx.x * 4 + w;
    const float4 xv = *(const float4*)(xin + row * 256 + lane * 4);
    const float4 yv = *(const float4*)(y + row * 256 + lane * 4);
    float4 sv;
    sv.x = xv.x + yv.x; sv.y = xv.y + yv.y; sv.z = xv.z + yv.z; sv.w = xv.w + yv.w;
    float sum = sv.x + sv.y + sv.z + sv.w;
    float sq  = sv.x * sv.x + sv.y * sv.y + sv.z * sv.z + sv.w * sv.w;
#pragma unroll
    for (int off = 1; off < 64; off <<= 1) {
        sum += __shfl_xor(sum, off, 64);
        sq  += __shfl_xor(sq, off, 64);
    }
    const float mu = sum * (1.f / 256.f);
    const float var = sq * (1.f / 256.f) - mu * mu;
    const float rs = rsqrtf(var + 1e-5f);
    const float4 gv = *(const float4*)(g + lane * 4);
    const float4 bv = *(const float4*)(bsh + lane * 4);
    float4 o;
    o.x = (sv.x - mu) * rs * gv.x + bv.x;
    o.y = (sv.y - mu) * rs * gv.y + bv.y;
    o.z = (sv.z - mu) * rs * gv.z + bv.z;
    o.w = (sv.w - mu) * rs * gv.w + bv.w;
    *(float4*)(xout + row * 256 + lane * 4) = o;
}

// ---------------------------------------------------------------------------
extern "C" void kernel_launch(void* const* d_in, const int* in_sizes, int n_in,
                              void* d_out, int out_size, void* d_ws, size_t ws_size,
                              hipStream_t stream)
{
    (void)in_sizes; (void)n_in; (void)out_size;
    const int*   tok   = (const int*)d_in[0];
    const int*   rel   = (const int*)d_in[1];
    const void*  mask  = d_in[2];
    const float* embed = (const float*)d_in[3];
    const float* W_in  = (const float*)d_in[4];
    const float* b_in  = (const float*)d_in[5];
    const float* Wq    = (const float*)d_in[6];
    const float* Wk    = (const float*)d_in[7];
    const float* Wv    = (const float*)d_in[8];
    const float* Wo    = (const float*)d_in[9];
    const float* ln1g  = (const float*)d_in[10];
    const float* ln1b  = (const float*)d_in[11];
    const float* ln2g  = (const float*)d_in[12];
    const float* ln2b  = (const float*)d_in[13];
    const float* W1    = (const float*)d_in[14];
    const float* b1    = (const float*)d_in[15];
    const float* W2    = (const float*)d_in[16];
    const float* b2    = (const float*)d_in[17];
    const float* relk  = (const float*)d_in[18];
    const float* relv  = (const float*)d_in[19];
    const float* Wout  = (const float*)d_in[20];
    const float* bout  = (const float*)d_in[21];
    float* out = (float*)d_out;

    float* ws  = (float*)d_ws;
    float* x   = ws;                       // 1M floats
    float* z   = ws + (1u << 20);          // 1M
    float* zo  = ws + 2u * (1u << 20);     // 1M
    float* qkv = ws + 3u * (1u << 20);     // 3M
    float* hb  = ws + 6u * (1u << 20);     // 4M  (FFN hidden; free during attn)

    const bool roomy = ws_size >= ((size_t)48 << 20);
    short* rel16 = roomy ? (short*)(ws + 10u * (1u << 20)) : (short*)hb;
    int*   flag  = (int*)(ws + (roomy ? 11u : 10u) * (1u << 20));

    detect_mask_kernel<<<1, 256, 0, stream>>>((const unsigned char*)mask, flag);
    if (roomy)
        prep_rel16<<<4096, 256, 0, stream>>>(rel, mask, flag, rel16);
    embed_proj_kernel<<<512, 256, 0, stream>>>(tok, embed, W_in, b_in, x);

    for (int l = 0; l < 4; ++l) {
        const float* wq = Wq + (size_t)l * 65536;
        const float* wk = Wk + (size_t)l * 65536;
        const float* wv = Wv + (size_t)l * 65536;
        const float* wo = Wo + (size_t)l * 65536;
        const float* w1 = W1 + (size_t)l * 262144;
        const float* w2 = W2 + (size_t)l * 262144;

        if (!roomy)
            prep_rel16<<<4096, 256, 0, stream>>>(rel, mask, flag, rel16);

        // fused QKV: [4096,256] @ 3x[256,256] -> qkv [4096,768]
        gemm_mfma<<<dim3(12, 64), 256, 0, stream>>>(x, wq, wk, wv, 256, nullptr,
                                                    qkv, NTOK, 256, 768, 0);
        attn_mfma<<<512, 256, 0, stream>>>(qkv, rel16, relk, relv, z);
        gemm_mfma<<<dim3(4, 64), 256, 0, stream>>>(z, wo, wo, wo, 256, nullptr,
                                                   zo, NTOK, 256, 256, 0);
        ln_kernel<<<1024, 256, 0, stream>>>(x, zo, ln1g + l * 256, ln1b + l * 256, x);
        gemm_mfma<<<dim3(16, 64), 256, 0, stream>>>(x, w1, w1, w1, 1024, b1 + l * 1024,
                                                    hb, NTOK, 256, 1024, 1);
        gemm_mfma<<<dim3(4, 64), 256, 0, stream>>>(hb, w2, w2, w2, 256, b2 + l * 256,
                                                   zo, NTOK, 1024, 256, 0);
        ln_kernel<<<1024, 256, 0, stream>>>(x, zo, ln2g + l * 256, ln2b + l * 256, x);
    }
    gemm_mfma<<<dim3(4, 64), 256, 0, stream>>>(x, Wout, Wout, Wout, 256, bout,
                                               out, NTOK, 256, 256, 0);
}